// Round 11
// baseline (1879.616 us; speedup 1.0000x reference)
//
#include <hip/hip_runtime.h>
#include <hip/hip_bf16.h>

// ---- problem constants ----
static constexpr int B_ = 16;
static constexpr int N_ = 8192;
static constexpr int C_ = 32;     // input feature channels
static constexpr int S_ = 1024;   // NPOINT
static constexpr int K_ = 32;     // NSAMPLE
static constexpr float BN_EPS_ = 1e-5f;

typedef float f32x2 __attribute__((ext_vector_type(2)));

__device__ __forceinline__ unsigned short f2bf(float f){
  unsigned u = __float_as_uint(f);
  unsigned r = (u + 0x7fffu + ((u >> 16) & 1u)) >> 16;
  return (unsigned short)r;
}
__device__ __forceinline__ float bflo(unsigned u){ return __int_as_float(u << 16); }
__device__ __forceinline__ float bfhi(unsigned u){ return __int_as_float(u & 0xffff0000u); }
__device__ __forceinline__ float bfu(unsigned short u){ return __int_as_float(((unsigned)u) << 16); }

// rocPRIM-standard wave64 DPP reduce step on a u64 key (HW-proven round 9/10).
template<int CTRL>
__device__ __forceinline__ unsigned long long dpp64(unsigned long long v){
  int lo = (int)(unsigned)(v & 0xffffffffull);
  int hi = (int)(unsigned)(v >> 32);
  int lo2 = __builtin_amdgcn_update_dpp(lo, lo, CTRL, 0xf, 0xf, false);
  int hi2 = __builtin_amdgcn_update_dpp(hi, hi, CTRL, 0xf, 0xf, false);
  return (((unsigned long long)(unsigned)hi2) << 32) | (unsigned)lo2;
}
__device__ __forceinline__ unsigned long long u64max(unsigned long long a,
                                                     unsigned long long b){
  return a > b ? a : b;
}

// ---- features (B,C,N) f32 -> featT (B,N,C) bf16 ----
__global__ __launch_bounds__(256) void transpose_kernel(const float* __restrict__ feat,
                                                        unsigned short* __restrict__ featT){
  __shared__ float tile[32][33];
  const int b = blockIdx.y;
  const int n0 = blockIdx.x * 32;
  const int tx = threadIdx.x, ty = threadIdx.y;
#pragma unroll
  for (int i = 0; i < 4; i++){
    int c = ty + i * 8;
    tile[c][tx] = feat[((size_t)b * C_ + c) * N_ + n0 + tx];
  }
  __syncthreads();
#pragma unroll
  for (int i = 0; i < 4; i++){
    int r = ty + i * 8;
    featT[((size_t)b * N_ + n0 + r) * C_ + tx] = f2bf(tile[tx][r]);
  }
}

// ---- furthest point sampling: 1 block/batch, 1024 threads, 1 barrier/iter ----
// Round-10 HW-proven skeleton (u64 key, 3-slot LDS atomicMax rotation, DPP
// reduce, LDS-broadcast centroid, value-only tracking + descending recovery
// scan, scalar-only asm pins). This round: 1024 threads x 8 pts/thread
// (4 waves/SIMD instead of 2) for latency hiding — same total VALU work,
// better stall overlap. Max tracking via single fmaxf chain (v_max3-fusable).
__global__ __launch_bounds__(1024) void fps_kernel(const float* __restrict__ xyz,
                                                   float* __restrict__ newxyz){
  const int b = blockIdx.x, t = threadIdx.x;      // t in [0,1024)
  const float* px = xyz + (size_t)b * N_ * 3;
  __shared__ float pl[N_ * 3];                    // 96 KB copy of the batch
  __shared__ unsigned long long slot[3];

  // coalesced global -> LDS copy
  for (int i = t; i < N_ * 3 / 4; i += 1024)
    ((float4*)pl)[i] = ((const float4*)px)[i];

  f32x2 X2[4], Y2[4], Z2[4], MD2[4];
#pragma unroll
  for (int q = 0; q < 4; q++){
    const int p0 = 2048 * q + t, p1 = 2048 * q + 1024 + t;
    float x0 = px[3 * p0 + 0], y0 = px[3 * p0 + 1], z0 = px[3 * p0 + 2];
    float x1 = px[3 * p1 + 0], y1 = px[3 * p1 + 1], z1 = px[3 * p1 + 2];
    asm volatile("" : "+v"(x0), "+v"(y0), "+v"(z0),
                      "+v"(x1), "+v"(y1), "+v"(z1));   // pin SCALARS in VGPRs
    X2[q] = f32x2{x0, x1};
    Y2[q] = f32x2{y0, y1};
    Z2[q] = f32x2{z0, z1};
    MD2[q] = f32x2{1e10f, 1e10f};
  }
  if (t == 0){
    slot[0] = 0ull; slot[1] = 0ull; slot[2] = 0ull;
    size_t o = (size_t)b * S_ * 3;
    newxyz[o] = px[0]; newxyz[o + 1] = px[1]; newxyz[o + 2] = px[2];
  }
  float cx = px[0], cy = px[1], cz = px[2];
  __syncthreads();                                // covers pl copy + slot init

  int cur = 1;                                    // slot index = i % 3
  for (int i = 1; i < S_; i++){
    const f32x2 cx2 = {cx, cx}, cy2 = {cy, cy}, cz2 = {cz, cz};
    float tmax = -1.f;
#pragma unroll
    for (int q = 0; q < 4; q++){
      f32x2 dx = X2[q] - cx2;                     // per-half rn sub
      f32x2 dy = Y2[q] - cy2;
      f32x2 dz = Z2[q] - cz2;
      f32x2 dd = (dx * dx + dy * dy) + dz * dz;   // exact reference op order
      f32x2 m;
      m[0] = fminf(MD2[q][0], dd[0]);
      m[1] = fminf(MD2[q][1], dd[1]);
      MD2[q] = m;
      tmax = fmaxf(tmax, fmaxf(m[0], m[1]));      // v_max3-fusable
    }
    // recover this thread's FIRST (smallest global) index attaining tmax:
    // descending q, high half (bigger idx) before low half -> later (smaller)
    // assignments overwrite.
    unsigned cand = 0;
#pragma unroll
    for (int q = 3; q >= 0; q--){
      if (MD2[q][1] == tmax) cand = (unsigned)(2048 * q + 1024 + t);
      if (MD2[q][0] == tmax) cand = (unsigned)(2048 * q + t);
    }
    // key: larger value wins; tie -> larger (8191-idx) -> smaller idx.
    unsigned long long key = ((unsigned long long)__float_as_uint(tmax) << 32)
                           | (unsigned long long)(8191u - cand);
    // wave64 DPP reduce -> lane 63 holds the wave max
    key = u64max(key, dpp64<0xb1>(key));          // quad_perm [1,0,3,2]
    key = u64max(key, dpp64<0x4e>(key));          // quad_perm [2,3,0,1]
    key = u64max(key, dpp64<0x114>(key));         // row_shr:4
    key = u64max(key, dpp64<0x118>(key));         // row_shr:8
    key = u64max(key, dpp64<0x142>(key));         // row_bcast:15
    key = u64max(key, dpp64<0x143>(key));         // row_bcast:31
    if ((t & 63) == 63) atomicMax(&slot[cur], key);   // 1 atomic per wave
    const int nxt = (cur == 2) ? 0 : cur + 1;
    if (t == 0) slot[nxt] = 0ull;   // zeroed pre-barrier; used next iter post-barrier
    __syncthreads();
    const unsigned long long best = slot[cur];
    const int fi = 8191 - (int)(best & 0xffffu);
    cx = pl[3 * fi]; cy = pl[3 * fi + 1]; cz = pl[3 * fi + 2];  // LDS broadcast
    if (t == 0){
      size_t o = ((size_t)b * S_ + i) * 3;
      newxyz[o] = cx; newxyz[o + 1] = cy; newxyz[o + 2] = cz;
    }
    cur = nxt;
  }
}

// ---- ball query: 1 wave per centroid ----
__global__ __launch_bounds__(256) void ballq_kernel(const float* __restrict__ xyz,
                                                    const float* __restrict__ newxyz,
                                                    int* __restrict__ idxout){
  const int wave = threadIdx.x >> 6, lane = threadIdx.x & 63;
  const int cid = blockIdx.x * 4 + wave;
  const int b = cid >> 10;
  const float cx = newxyz[(size_t)cid * 3];
  const float cy = newxyz[(size_t)cid * 3 + 1];
  const float cz = newxyz[(size_t)cid * 3 + 2];
  const float* px = xyz + (size_t)b * N_ * 3;
  __shared__ int buf[4][32];
  const float r2 = 0.04f;   // fp32(double(0.2*0.2)) == 0x3D23D70A
  int have = 0;
  for (int base = 0; base < N_ && have < 32; base += 64){
    int p = base + lane;
    float dx = __fsub_rn(cx, px[3 * p]);
    float dy = __fsub_rn(cy, px[3 * p + 1]);
    float dz = __fsub_rn(cz, px[3 * p + 2]);
    float sq = __fadd_rn(__fadd_rn(__fmul_rn(dx, dx), __fmul_rn(dy, dy)), __fmul_rn(dz, dz));
    bool pred = sq < r2;
    unsigned long long m = __ballot(pred);
    if (pred){
      int pos = have + __popcll(m & ((1ull << lane) - 1ull));
      if (pos < 32) buf[wave][pos] = p;
    }
    have += (int)__popcll(m);
  }
  __syncthreads();
  if (lane < 32){
    int first = buf[wave][0];
    int v = (lane < have) ? buf[wave][lane] : first;
    idxout[(size_t)cid * 32 + lane] = v;
  }
}

// ---- LDS arena layout for the recompute pass kernels ----
template<int DEPTH>
struct PassLds {
  static constexpr int XS  = 0;                 // [32][36] f32 (x tile, col35 zeroed)
  static constexpr int W1O = XS + 32 * 36;      // [64][36] f32 (col35 zeroed)
  static constexpr int HA  = W1O + 64 * 36;     // [32][68] f32 (DEPTH>=2)
  static constexpr int W2O = HA + 32 * 68;      // [64][64] f32
  static constexpr int HB  = W2O + 64 * 64;     // [32][68] f32 (DEPTH==3)
  static constexpr int W3O = HB + 32 * 68;      // [128][64] bf16 -> 4096 f32 slots
  static constexpr int FLOATS = (DEPTH == 1) ? (W1O + 64 * 36)
                             : (DEPTH == 2) ? (W2O + 64 * 64)
                             : (W3O + 4096);    // D3: 16000 floats = 64000 B
};

// ---- fused recompute pass (512 threads: row = t&31, grp = t>>5 in [0,16)) ----
template<int DEPTH, bool FT>
__global__ __launch_bounds__(512) void pass_kernel(
    const float* __restrict__ xyz, const float* __restrict__ feat,
    const unsigned short* __restrict__ featT, const float* __restrict__ newxyz,
    const int* __restrict__ idx,
    const float* __restrict__ W1, const float* __restrict__ W2,
    const float* __restrict__ W3,
    const float* __restrict__ sab1, const float* __restrict__ sab2,
    float* __restrict__ partials,
    unsigned short* __restrict__ m3max, unsigned short* __restrict__ m3min){
  using L = PassLds<DEPTH>;
  __shared__ float sm[L::FLOATS];
  const int t = threadIdx.x;
  const int row = t & 31, grp = t >> 5;   // sample-row, channel-group

  // ---- stage weights once per block ----
  for (int i = t; i < 64 * 36; i += 512){
    int o = i / 36, c = i - o * 36;
    sm[L::W1O + i] = (c < 35) ? W1[o * 35 + c] : 0.f;
  }
  if constexpr (DEPTH >= 2){
    for (int i = t; i < 64 * 64; i += 512) sm[L::W2O + i] = W2[i];
  }
  unsigned short* w3p = nullptr;
  if constexpr (DEPTH == 3){
    w3p = (unsigned short*)&sm[L::W3O];
    for (int i = t; i < 128 * 64; i += 512) w3p[i] = f2bf(W3[i]);
  }

  // ---- per-thread BN params ----
  float sa1[4], sb1[4], sa2[4], sb2[4];
  if constexpr (DEPTH >= 2){
#pragma unroll
    for (int u = 0; u < 4; u++){ sa1[u] = sab1[grp * 4 + u]; sb1[u] = sab1[64 + grp * 4 + u]; }
  }
  if constexpr (DEPTH == 3){
#pragma unroll
    for (int u = 0; u < 4; u++){ sa2[u] = sab2[grp * 4 + u]; sb2[u] = sab2[64 + grp * 4 + u]; }
  }

  constexpr int US = (DEPTH == 3) ? 8 : 4;     // stats channels per thread
  float stS[US], stQ[US];
#pragma unroll
  for (int u = 0; u < US; u++){ stS[u] = 0.f; stQ[u] = 0.f; }

  for (int it = 0; it < 32; ++it){
    const int g = blockIdx.x * 32 + it;
    const int b = g >> 10;
    if constexpr (DEPTH == 1) __syncthreads();  // protect XS from prev readers

    // ---- gather x tile: [32 pts][3 rel-coords | 32 feats | 0 pad] ----
    {
      float* xr = &sm[L::XS + row * 36];
      if constexpr (FT){
        if (grp < 4){
          const int id = idx[(size_t)g * 32 + row];
          const uint4 f = *(const uint4*)(featT + ((size_t)b * N_ + id) * C_ + grp * 8);
          xr[3 + grp * 8 + 0] = bflo(f.x); xr[3 + grp * 8 + 1] = bfhi(f.x);
          xr[3 + grp * 8 + 2] = bflo(f.y); xr[3 + grp * 8 + 3] = bfhi(f.y);
          xr[3 + grp * 8 + 4] = bflo(f.z); xr[3 + grp * 8 + 5] = bfhi(f.z);
          xr[3 + grp * 8 + 6] = bflo(f.w); xr[3 + grp * 8 + 7] = bfhi(f.w);
        } else if (grp == 4){
          const int id = idx[(size_t)g * 32 + row];
          size_t pb = ((size_t)b * N_ + id) * 3;
          xr[0] = __fsub_rn(xyz[pb + 0], newxyz[(size_t)g * 3 + 0]);
          xr[1] = __fsub_rn(xyz[pb + 1], newxyz[(size_t)g * 3 + 1]);
          xr[2] = __fsub_rn(xyz[pb + 2], newxyz[(size_t)g * 3 + 2]);
          xr[35] = 0.f;
        }
      } else {
        if (grp < 8){
          const int id = idx[(size_t)g * 32 + row];
#pragma unroll
          for (int q = 0; q < 4; q++)
            xr[3 + grp * 4 + q] = feat[((size_t)b * C_ + grp * 4 + q) * N_ + id];
        } else if (grp == 8){
          const int id = idx[(size_t)g * 32 + row];
          size_t pb = ((size_t)b * N_ + id) * 3;
          xr[0] = __fsub_rn(xyz[pb + 0], newxyz[(size_t)g * 3 + 0]);
          xr[1] = __fsub_rn(xyz[pb + 1], newxyz[(size_t)g * 3 + 1]);
          xr[2] = __fsub_rn(xyz[pb + 2], newxyz[(size_t)g * 3 + 2]);
          xr[35] = 0.f;
        }
      }
    }
    __syncthreads();

    // ---- mm1: y1[row][grp*4+u] ----
    float acc[4] = {0.f, 0.f, 0.f, 0.f};
#pragma unroll 3
    for (int cb = 0; cb < 36; cb += 4){
      const float4 xv = *(const float4*)&sm[L::XS + row * 36 + cb];
#pragma unroll
      for (int u = 0; u < 4; u++){
        const float4 wv = *(const float4*)&sm[L::W1O + (grp * 4 + u) * 36 + cb];
        acc[u] = fmaf(xv.x, wv.x, acc[u]);
        acc[u] = fmaf(xv.y, wv.y, acc[u]);
        acc[u] = fmaf(xv.z, wv.z, acc[u]);
        acc[u] = fmaf(xv.w, wv.w, acc[u]);
      }
    }
    if constexpr (DEPTH == 1){
#pragma unroll
      for (int u = 0; u < 4; u++){ stS[u] += acc[u]; stQ[u] = fmaf(acc[u], acc[u], stQ[u]); }
      continue;
    }

    if constexpr (DEPTH >= 2){
      // ---- bn1 + relu -> hA ----
#pragma unroll
      for (int u = 0; u < 4; u++)
        sm[L::HA + row * 68 + grp * 4 + u] = fmaxf(fmaf(acc[u], sa1[u], sb1[u]), 0.f);
      __syncthreads();

      // ---- mm2 ----
      float acc2[4] = {0.f, 0.f, 0.f, 0.f};
#pragma unroll 4
      for (int cb = 0; cb < 64; cb += 4){
        const float4 xv = *(const float4*)&sm[L::HA + row * 68 + cb];
#pragma unroll
        for (int u = 0; u < 4; u++){
          const float4 wv = *(const float4*)&sm[L::W2O + (grp * 4 + u) * 64 + cb];
          acc2[u] = fmaf(xv.x, wv.x, acc2[u]);
          acc2[u] = fmaf(xv.y, wv.y, acc2[u]);
          acc2[u] = fmaf(xv.z, wv.z, acc2[u]);
          acc2[u] = fmaf(xv.w, wv.w, acc2[u]);
        }
      }
      if constexpr (DEPTH == 2){
#pragma unroll
        for (int u = 0; u < 4; u++){ stS[u] += acc2[u]; stQ[u] = fmaf(acc2[u], acc2[u], stQ[u]); }
        continue;
      }

      if constexpr (DEPTH == 3){
        // ---- bn2 + relu -> hB ----
#pragma unroll
        for (int u = 0; u < 4; u++)
          sm[L::HB + row * 68 + grp * 4 + u] = fmaxf(fmaf(acc2[u], sa2[u], sb2[u]), 0.f);
        __syncthreads();

        // ---- mm3: y3[row][grp*8+u], W3 bf16 in LDS ----
        float acc3[8];
#pragma unroll
        for (int u = 0; u < 8; u++) acc3[u] = 0.f;
#pragma unroll 2
        for (int cb = 0; cb < 64; cb += 4){
          const float4 xv = *(const float4*)&sm[L::HB + row * 68 + cb];
#pragma unroll
          for (int u = 0; u < 8; u++){
            const uint2 wp = *(const uint2*)&w3p[(grp * 8 + u) * 64 + cb];
            acc3[u] = fmaf(xv.x, bflo(wp.x), acc3[u]);
            acc3[u] = fmaf(xv.y, bfhi(wp.x), acc3[u]);
            acc3[u] = fmaf(xv.z, bflo(wp.y), acc3[u]);
            acc3[u] = fmaf(xv.w, bfhi(wp.y), acc3[u]);
          }
        }
#pragma unroll
        for (int u = 0; u < 8; u++){ stS[u] += acc3[u]; stQ[u] = fmaf(acc3[u], acc3[u], stQ[u]); }

        // ---- pre-BN max/min over the 32 rows (lanes within half-wave) ----
        const int s = g & 1023;
#pragma unroll
        for (int u = 0; u < 8; u++){
          float mx = acc3[u], mn = acc3[u];
#pragma unroll
          for (int m = 1; m < 32; m <<= 1){
            mx = fmaxf(mx, __shfl_xor(mx, m));
            mn = fminf(mn, __shfl_xor(mn, m));
          }
          if (row == 0){
            size_t o = ((size_t)b * 128 + grp * 8 + u) * 1024 + s;
            m3max[o] = f2bf(mx); m3min[o] = f2bf(mn);
          }
        }
      }
    }
  }

  // ---- block stats partials: reduce over rows (half-wave lanes) ----
#pragma unroll
  for (int m = 1; m < 32; m <<= 1){
#pragma unroll
    for (int u = 0; u < US; u++){
      stS[u] += __shfl_xor(stS[u], m);
      stQ[u] += __shfl_xor(stQ[u], m);
    }
  }
  if (row == 0){
    constexpr int CH = (DEPTH == 3) ? 128 : 64;
    float* p = partials + (size_t)blockIdx.x * (2 * CH);
    const int o0 = grp * US;
#pragma unroll
    for (int u = 0; u < US; u++){ p[o0 + u] = stS[u]; p[CH + o0 + u] = stQ[u]; }
  }
}

// ---- stats stage 2: reduce 512 partial rows, emit per-channel scale/shift ----
template<int CH>
__global__ __launch_bounds__(256) void stats_fin(const float* __restrict__ partials,
                                                 const float* __restrict__ g,
                                                 const float* __restrict__ bet,
                                                 float* __restrict__ sab){
  const int t = threadIdx.x;
  __shared__ float red[2 * CH];
  if (t < 2 * CH){
    float a = 0.f;
#pragma unroll 8
    for (int r = 0; r < 512; r++) a += partials[(size_t)r * (2 * CH) + t];
    red[t] = a;
  }
  __syncthreads();
  if (t < CH){
    constexpr float inv = 1.f / (float)((size_t)B_ * S_ * K_);
    float mean = red[t] * inv;
    float var  = red[CH + t] * inv - mean * mean;
    float r    = 1.f / sqrtf(var + BN_EPS_);
    float a    = r * g[t];
    sab[t] = a;
    sab[CH + t] = bet[t] - mean * a;
  }
}

// ---- final: bn3(+relu) on bf16 pre-BN max/min (monotone-affine dispatch) ----
__global__ __launch_bounds__(256) void final_kernel(const unsigned short* __restrict__ m3max,
                                                    const unsigned short* __restrict__ m3min,
                                                    const float* __restrict__ sab3,
                                                    float* __restrict__ outNF){
  const int q = blockIdx.x * 256 + threadIdx.x;   // quad index over B*128*1024/4
  const int e = q * 4;
  const int o = (e >> 10) & 127;
  const float a = sab3[o], c = sab3[128 + o];
  const ushort4 mx = ((const ushort4*)m3max)[q];
  const ushort4 mn = ((const ushort4*)m3min)[q];
  float4 r;
  r.x = fmaxf(fmaf(bfu(a >= 0.f ? mx.x : mn.x), a, c), 0.f);
  r.y = fmaxf(fmaf(bfu(a >= 0.f ? mx.y : mn.y), a, c), 0.f);
  r.z = fmaxf(fmaf(bfu(a >= 0.f ? mx.z : mn.z), a, c), 0.f);
  r.w = fmaxf(fmaf(bfu(a >= 0.f ? mx.w : mn.w), a, c), 0.f);
  ((float4*)outNF)[q] = r;
}

extern "C" void kernel_launch(void* const* d_in, const int* in_sizes, int n_in,
                              void* d_out, int out_size, void* d_ws, size_t ws_size,
                              hipStream_t stream){
  (void)in_sizes; (void)n_in; (void)out_size;
  const float* xyz = (const float*)d_in[0];
  const float* feat = (const float*)d_in[1];
  const float* W1 = (const float*)d_in[2];
  const float* g1 = (const float*)d_in[3];
  const float* b1 = (const float*)d_in[4];
  const float* W2 = (const float*)d_in[5];
  const float* g2 = (const float*)d_in[6];
  const float* b2 = (const float*)d_in[7];
  const float* W3 = (const float*)d_in[8];
  const float* g3 = (const float*)d_in[9];
  const float* b3 = (const float*)d_in[10];

  float* newxyz = (float*)d_out;                       // (B,S,3)
  float* outNF  = newxyz + (size_t)B_ * S_ * 3;        // (B,128,S)
  char* ws = (char*)d_ws;

  size_t off = 0;
  auto alloc = [&](size_t bytes){ size_t o = off; off += (bytes + 255) & ~(size_t)255; return o; };
  size_t o_idx  = alloc((size_t)B_ * S_ * K_ * 4);           // 2 MB
  size_t o_part = alloc((size_t)512 * 256 * 4);              // 512 KB
  size_t o_sab1 = alloc(1024);
  size_t o_sab2 = alloc(1024);
  size_t o_sab3 = alloc(1024);
  size_t o_m3mx = alloc((size_t)B_ * S_ * 128 * 2);          // 4 MB (bf16)
  size_t o_m3mn = alloc((size_t)B_ * S_ * 128 * 2);          // 4 MB (bf16)
  size_t o_featT = alloc((size_t)B_ * N_ * C_ * 2);          // 8 MB (bf16)
  const bool ft = ws_size >= off;                            // 19.4 MB total

  int*   idxp  = (int*)(ws + o_idx);
  float* part  = (float*)(ws + o_part);
  float* sab1  = (float*)(ws + o_sab1);
  float* sab2  = (float*)(ws + o_sab2);
  float* sab3  = (float*)(ws + o_sab3);
  unsigned short* m3mx  = (unsigned short*)(ws + o_m3mx);
  unsigned short* m3mn  = (unsigned short*)(ws + o_m3mn);
  unsigned short* featT = (unsigned short*)(ws + o_featT);

  if (ft) transpose_kernel<<<dim3(N_ / 32, B_), dim3(32, 8), 0, stream>>>(feat, featT);
  fps_kernel<<<B_, 1024, 0, stream>>>(xyz, newxyz);
  ballq_kernel<<<B_ * S_ / 4, 256, 0, stream>>>(xyz, newxyz, idxp);

  if (ft){
    pass_kernel<1, true><<<512, 512, 0, stream>>>(xyz, feat, featT, newxyz, idxp,
        W1, W2, W3, sab1, sab2, part, m3mx, m3mn);
    stats_fin<64><<<1, 256, 0, stream>>>(part, g1, b1, sab1);
    pass_kernel<2, true><<<512, 512, 0, stream>>>(xyz, feat, featT, newxyz, idxp,
        W1, W2, W3, sab1, sab2, part, m3mx, m3mn);
    stats_fin<64><<<1, 256, 0, stream>>>(part, g2, b2, sab2);
    pass_kernel<3, true><<<512, 512, 0, stream>>>(xyz, feat, featT, newxyz, idxp,
        W1, W2, W3, sab1, sab2, part, m3mx, m3mn);
    stats_fin<128><<<1, 256, 0, stream>>>(part, g3, b3, sab3);
  } else {
    pass_kernel<1, false><<<512, 512, 0, stream>>>(xyz, feat, featT, newxyz, idxp,
        W1, W2, W3, sab1, sab2, part, m3mx, m3mn);
    stats_fin<64><<<1, 256, 0, stream>>>(part, g1, b1, sab1);
    pass_kernel<2, false><<<512, 512, 0, stream>>>(xyz, feat, featT, newxyz, idxp,
        W1, W2, W3, sab1, sab2, part, m3mx, m3mn);
    stats_fin<64><<<1, 256, 0, stream>>>(part, g2, b2, sab2);
    pass_kernel<3, false><<<512, 512, 0, stream>>>(xyz, feat, featT, newxyz, idxp,
        W1, W2, W3, sab1, sab2, part, m3mx, m3mn);
    stats_fin<128><<<1, 256, 0, stream>>>(part, g3, b3, sab3);
  }
  final_kernel<<<(B_ * 128 * S_) / 1024, 256, 0, stream>>>(m3mx, m3mn, sab3, outNF);
}

// Round 13
// 1738.630 us; speedup vs baseline: 1.0811x; 1.0811x over previous
//
#include <hip/hip_runtime.h>
#include <hip/hip_bf16.h>

// ---- problem constants ----
static constexpr int B_ = 16;
static constexpr int N_ = 8192;
static constexpr int C_ = 32;     // input feature channels
static constexpr int S_ = 1024;   // NPOINT
static constexpr int K_ = 32;     // NSAMPLE
static constexpr float BN_EPS_ = 1e-5f;

typedef float f32x2 __attribute__((ext_vector_type(2)));

__device__ __forceinline__ unsigned short f2bf(float f){
  unsigned u = __float_as_uint(f);
  unsigned r = (u + 0x7fffu + ((u >> 16) & 1u)) >> 16;
  return (unsigned short)r;
}
__device__ __forceinline__ float bflo(unsigned u){ return __int_as_float(u << 16); }
__device__ __forceinline__ float bfhi(unsigned u){ return __int_as_float(u & 0xffff0000u); }
__device__ __forceinline__ float bfu(unsigned short u){ return __int_as_float(((unsigned)u) << 16); }

// rocPRIM-standard wave64 DPP reduce step on a u64 key (HW-proven R9/R10).
template<int CTRL>
__device__ __forceinline__ unsigned long long dpp64(unsigned long long v){
  int lo = (int)(unsigned)(v & 0xffffffffull);
  int hi = (int)(unsigned)(v >> 32);
  int lo2 = __builtin_amdgcn_update_dpp(lo, lo, CTRL, 0xf, 0xf, false);
  int hi2 = __builtin_amdgcn_update_dpp(hi, hi, CTRL, 0xf, 0xf, false);
  return (((unsigned long long)(unsigned)hi2) << 32) | (unsigned)lo2;
}
__device__ __forceinline__ unsigned long long u64max(unsigned long long a,
                                                     unsigned long long b){
  return a > b ? a : b;
}

// ---- features (B,C,N) f32 -> featT (B,N,C) bf16 ----
__global__ __launch_bounds__(256) void transpose_kernel(const float* __restrict__ feat,
                                                        unsigned short* __restrict__ featT){
  __shared__ float tile[32][33];
  const int b = blockIdx.y;
  const int n0 = blockIdx.x * 32;
  const int tx = threadIdx.x, ty = threadIdx.y;
#pragma unroll
  for (int i = 0; i < 4; i++){
    int c = ty + i * 8;
    tile[c][tx] = feat[((size_t)b * C_ + c) * N_ + n0 + tx];
  }
  __syncthreads();
#pragma unroll
  for (int i = 0; i < 4; i++){
    int r = ty + i * 8;
    featT[((size_t)b * N_ + n0 + r) * C_ + tx] = f2bf(tile[tx][r]);
  }
}

// ---- furthest point sampling: 1 block/batch, 256 threads, 1 barrier/iter ----
// Exact R10 HW-proven skeleton (plain-C f32x2 distance math — per-half IEEE rn,
// scalar-only asm pins, u64 key, DPP reduce, 3-slot LDS atomicMax rotation,
// LDS-broadcast centroid, value-only tracking + descending recovery scan).
// Single change vs R10: 256 threads x 32 pts/thread (4 waves) — same per-SIMD
// issue work, but half the per-wave reduce/atomic/barrier overhead (R11 showed
// overhead scales with wave count; this probes the other direction).
__global__ __launch_bounds__(256) void fps_kernel(const float* __restrict__ xyz,
                                                  float* __restrict__ newxyz){
  const int b = blockIdx.x, t = threadIdx.x;      // t in [0,256)
  const float* px = xyz + (size_t)b * N_ * 3;
  __shared__ float pl[N_ * 3];                    // 96 KB copy of the batch
  __shared__ unsigned long long slot[3];

  // coalesced global -> LDS copy
  for (int i = t; i < N_ * 3 / 4; i += 256)
    ((float4*)pl)[i] = ((const float4*)px)[i];

  f32x2 X2[16], Y2[16], Z2[16], MD2[16];
#pragma unroll
  for (int q = 0; q < 16; q++){
    const int p0 = 512 * q + t, p1 = 512 * q + 256 + t;
    float x0 = px[3 * p0 + 0], y0 = px[3 * p0 + 1], z0 = px[3 * p0 + 2];
    float x1 = px[3 * p1 + 0], y1 = px[3 * p1 + 1], z1 = px[3 * p1 + 2];
    asm volatile("" : "+v"(x0), "+v"(y0), "+v"(z0),
                      "+v"(x1), "+v"(y1), "+v"(z1));   // pin SCALARS in VGPRs
    X2[q] = f32x2{x0, x1};
    Y2[q] = f32x2{y0, y1};
    Z2[q] = f32x2{z0, z1};
    MD2[q] = f32x2{1e10f, 1e10f};
  }
  if (t == 0){
    slot[0] = 0ull; slot[1] = 0ull; slot[2] = 0ull;
    size_t o = (size_t)b * S_ * 3;
    newxyz[o] = px[0]; newxyz[o + 1] = px[1]; newxyz[o + 2] = px[2];
  }
  float cx = px[0], cy = px[1], cz = px[2];
  __syncthreads();                                // covers pl copy + slot init

  int cur = 1;                                    // slot index = i % 3
  for (int i = 1; i < S_; i++){
    const f32x2 cx2 = {cx, cx}, cy2 = {cy, cy}, cz2 = {cz, cz};
    float tmax = -1.f;
#pragma unroll
    for (int q = 0; q < 16; q++){
      f32x2 dx = X2[q] - cx2;                     // per-half rn sub
      f32x2 dy = Y2[q] - cy2;
      f32x2 dz = Z2[q] - cz2;
      f32x2 dd = (dx * dx + dy * dy) + dz * dz;   // exact reference op order
      f32x2 m;
      m[0] = fminf(MD2[q][0], dd[0]);
      m[1] = fminf(MD2[q][1], dd[1]);
      MD2[q] = m;
      tmax = fmaxf(tmax, fmaxf(m[0], m[1]));      // v_max3-fusable
    }
    // recover this thread's FIRST (smallest global) index attaining tmax:
    // descending q, high half (bigger idx) before low half -> later (smaller)
    // assignments overwrite.
    unsigned cand = 0;
#pragma unroll
    for (int q = 15; q >= 0; q--){
      if (MD2[q][1] == tmax) cand = (unsigned)(512 * q + 256 + t);
      if (MD2[q][0] == tmax) cand = (unsigned)(512 * q + t);
    }
    // key: larger value wins; tie -> larger (8191-idx) -> smaller idx.
    unsigned long long key = ((unsigned long long)__float_as_uint(tmax) << 32)
                           | (unsigned long long)(8191u - cand);
    // wave64 DPP reduce -> lane 63 holds the wave max
    key = u64max(key, dpp64<0xb1>(key));          // quad_perm [1,0,3,2]
    key = u64max(key, dpp64<0x4e>(key));          // quad_perm [2,3,0,1]
    key = u64max(key, dpp64<0x114>(key));         // row_shr:4
    key = u64max(key, dpp64<0x118>(key));         // row_shr:8
    key = u64max(key, dpp64<0x142>(key));         // row_bcast:15
    key = u64max(key, dpp64<0x143>(key));         // row_bcast:31
    if ((t & 63) == 63) atomicMax(&slot[cur], key);   // 1 atomic per wave (4 total)
    const int nxt = (cur == 2) ? 0 : cur + 1;
    if (t == 0) slot[nxt] = 0ull;   // zeroed pre-barrier; used next iter post-barrier
    __syncthreads();
    const unsigned long long best = slot[cur];
    const int fi = 8191 - (int)(best & 0xffffu);
    cx = pl[3 * fi]; cy = pl[3 * fi + 1]; cz = pl[3 * fi + 2];  // LDS broadcast
    if (t == 0){
      size_t o = ((size_t)b * S_ + i) * 3;
      newxyz[o] = cx; newxyz[o + 1] = cy; newxyz[o + 2] = cz;
    }
    cur = nxt;
  }
}

// ---- ball query: 1 wave per centroid ----
__global__ __launch_bounds__(256) void ballq_kernel(const float* __restrict__ xyz,
                                                    const float* __restrict__ newxyz,
                                                    int* __restrict__ idxout){
  const int wave = threadIdx.x >> 6, lane = threadIdx.x & 63;
  const int cid = blockIdx.x * 4 + wave;
  const int b = cid >> 10;
  const float cx = newxyz[(size_t)cid * 3];
  const float cy = newxyz[(size_t)cid * 3 + 1];
  const float cz = newxyz[(size_t)cid * 3 + 2];
  const float* px = xyz + (size_t)b * N_ * 3;
  __shared__ int buf[4][32];
  const float r2 = 0.04f;   // fp32(double(0.2*0.2)) == 0x3D23D70A
  int have = 0;
  for (int base = 0; base < N_ && have < 32; base += 64){
    int p = base + lane;
    float dx = __fsub_rn(cx, px[3 * p]);
    float dy = __fsub_rn(cy, px[3 * p + 1]);
    float dz = __fsub_rn(cz, px[3 * p + 2]);
    float sq = __fadd_rn(__fadd_rn(__fmul_rn(dx, dx), __fmul_rn(dy, dy)), __fmul_rn(dz, dz));
    bool pred = sq < r2;
    unsigned long long m = __ballot(pred);
    if (pred){
      int pos = have + __popcll(m & ((1ull << lane) - 1ull));
      if (pos < 32) buf[wave][pos] = p;
    }
    have += (int)__popcll(m);
  }
  __syncthreads();
  if (lane < 32){
    int first = buf[wave][0];
    int v = (lane < have) ? buf[wave][lane] : first;
    idxout[(size_t)cid * 32 + lane] = v;
  }
}

// ---- LDS arena layout for the recompute pass kernels ----
template<int DEPTH>
struct PassLds {
  static constexpr int XS  = 0;                 // [32][36] f32 (x tile, col35 zeroed)
  static constexpr int W1O = XS + 32 * 36;      // [64][36] f32 (col35 zeroed)
  static constexpr int HA  = W1O + 64 * 36;     // [32][68] f32 (DEPTH>=2)
  static constexpr int W2O = HA + 32 * 68;      // [64][64] f32
  static constexpr int HB  = W2O + 64 * 64;     // [32][68] f32 (DEPTH==3)
  static constexpr int W3O = HB + 32 * 68;      // [128][64] bf16 -> 4096 f32 slots
  static constexpr int FLOATS = (DEPTH == 1) ? (W1O + 64 * 36)
                             : (DEPTH == 2) ? (W2O + 64 * 64)
                             : (W3O + 4096);    // D3: 16000 floats = 64000 B
};

// ---- fused recompute pass (512 threads: row = t&31, grp = t>>5 in [0,16)) ----
template<int DEPTH, bool FT>
__global__ __launch_bounds__(512) void pass_kernel(
    const float* __restrict__ xyz, const float* __restrict__ feat,
    const unsigned short* __restrict__ featT, const float* __restrict__ newxyz,
    const int* __restrict__ idx,
    const float* __restrict__ W1, const float* __restrict__ W2,
    const float* __restrict__ W3,
    const float* __restrict__ sab1, const float* __restrict__ sab2,
    float* __restrict__ partials,
    unsigned short* __restrict__ m3max, unsigned short* __restrict__ m3min){
  using L = PassLds<DEPTH>;
  __shared__ float sm[L::FLOATS];
  const int t = threadIdx.x;
  const int row = t & 31, grp = t >> 5;   // sample-row, channel-group

  // ---- stage weights once per block ----
  for (int i = t; i < 64 * 36; i += 512){
    int o = i / 36, c = i - o * 36;
    sm[L::W1O + i] = (c < 35) ? W1[o * 35 + c] : 0.f;
  }
  if constexpr (DEPTH >= 2){
    for (int i = t; i < 64 * 64; i += 512) sm[L::W2O + i] = W2[i];
  }
  unsigned short* w3p = nullptr;
  if constexpr (DEPTH == 3){
    w3p = (unsigned short*)&sm[L::W3O];
    for (int i = t; i < 128 * 64; i += 512) w3p[i] = f2bf(W3[i]);
  }

  // ---- per-thread BN params ----
  float sa1[4], sb1[4], sa2[4], sb2[4];
  if constexpr (DEPTH >= 2){
#pragma unroll
    for (int u = 0; u < 4; u++){ sa1[u] = sab1[grp * 4 + u]; sb1[u] = sab1[64 + grp * 4 + u]; }
  }
  if constexpr (DEPTH == 3){
#pragma unroll
    for (int u = 0; u < 4; u++){ sa2[u] = sab2[grp * 4 + u]; sb2[u] = sab2[64 + grp * 4 + u]; }
  }

  constexpr int US = (DEPTH == 3) ? 8 : 4;     // stats channels per thread
  float stS[US], stQ[US];
#pragma unroll
  for (int u = 0; u < US; u++){ stS[u] = 0.f; stQ[u] = 0.f; }

  for (int it = 0; it < 32; ++it){
    const int g = blockIdx.x * 32 + it;
    const int b = g >> 10;
    if constexpr (DEPTH == 1) __syncthreads();  // protect XS from prev readers

    // ---- gather x tile: [32 pts][3 rel-coords | 32 feats | 0 pad] ----
    {
      float* xr = &sm[L::XS + row * 36];
      if constexpr (FT){
        if (grp < 4){
          const int id = idx[(size_t)g * 32 + row];
          const uint4 f = *(const uint4*)(featT + ((size_t)b * N_ + id) * C_ + grp * 8);
          xr[3 + grp * 8 + 0] = bflo(f.x); xr[3 + grp * 8 + 1] = bfhi(f.x);
          xr[3 + grp * 8 + 2] = bflo(f.y); xr[3 + grp * 8 + 3] = bfhi(f.y);
          xr[3 + grp * 8 + 4] = bflo(f.z); xr[3 + grp * 8 + 5] = bfhi(f.z);
          xr[3 + grp * 8 + 6] = bflo(f.w); xr[3 + grp * 8 + 7] = bfhi(f.w);
        } else if (grp == 4){
          const int id = idx[(size_t)g * 32 + row];
          size_t pb = ((size_t)b * N_ + id) * 3;
          xr[0] = __fsub_rn(xyz[pb + 0], newxyz[(size_t)g * 3 + 0]);
          xr[1] = __fsub_rn(xyz[pb + 1], newxyz[(size_t)g * 3 + 1]);
          xr[2] = __fsub_rn(xyz[pb + 2], newxyz[(size_t)g * 3 + 2]);
          xr[35] = 0.f;
        }
      } else {
        if (grp < 8){
          const int id = idx[(size_t)g * 32 + row];
#pragma unroll
          for (int q = 0; q < 4; q++)
            xr[3 + grp * 4 + q] = feat[((size_t)b * C_ + grp * 4 + q) * N_ + id];
        } else if (grp == 8){
          const int id = idx[(size_t)g * 32 + row];
          size_t pb = ((size_t)b * N_ + id) * 3;
          xr[0] = __fsub_rn(xyz[pb + 0], newxyz[(size_t)g * 3 + 0]);
          xr[1] = __fsub_rn(xyz[pb + 1], newxyz[(size_t)g * 3 + 1]);
          xr[2] = __fsub_rn(xyz[pb + 2], newxyz[(size_t)g * 3 + 2]);
          xr[35] = 0.f;
        }
      }
    }
    __syncthreads();

    // ---- mm1: y1[row][grp*4+u] ----
    float acc[4] = {0.f, 0.f, 0.f, 0.f};
#pragma unroll 3
    for (int cb = 0; cb < 36; cb += 4){
      const float4 xv = *(const float4*)&sm[L::XS + row * 36 + cb];
#pragma unroll
      for (int u = 0; u < 4; u++){
        const float4 wv = *(const float4*)&sm[L::W1O + (grp * 4 + u) * 36 + cb];
        acc[u] = fmaf(xv.x, wv.x, acc[u]);
        acc[u] = fmaf(xv.y, wv.y, acc[u]);
        acc[u] = fmaf(xv.z, wv.z, acc[u]);
        acc[u] = fmaf(xv.w, wv.w, acc[u]);
      }
    }
    if constexpr (DEPTH == 1){
#pragma unroll
      for (int u = 0; u < 4; u++){ stS[u] += acc[u]; stQ[u] = fmaf(acc[u], acc[u], stQ[u]); }
      continue;
    }

    if constexpr (DEPTH >= 2){
      // ---- bn1 + relu -> hA ----
#pragma unroll
      for (int u = 0; u < 4; u++)
        sm[L::HA + row * 68 + grp * 4 + u] = fmaxf(fmaf(acc[u], sa1[u], sb1[u]), 0.f);
      __syncthreads();

      // ---- mm2 ----
      float acc2[4] = {0.f, 0.f, 0.f, 0.f};
#pragma unroll 4
      for (int cb = 0; cb < 64; cb += 4){
        const float4 xv = *(const float4*)&sm[L::HA + row * 68 + cb];
#pragma unroll
        for (int u = 0; u < 4; u++){
          const float4 wv = *(const float4*)&sm[L::W2O + (grp * 4 + u) * 64 + cb];
          acc2[u] = fmaf(xv.x, wv.x, acc2[u]);
          acc2[u] = fmaf(xv.y, wv.y, acc2[u]);
          acc2[u] = fmaf(xv.z, wv.z, acc2[u]);
          acc2[u] = fmaf(xv.w, wv.w, acc2[u]);
        }
      }
      if constexpr (DEPTH == 2){
#pragma unroll
        for (int u = 0; u < 4; u++){ stS[u] += acc2[u]; stQ[u] = fmaf(acc2[u], acc2[u], stQ[u]); }
        continue;
      }

      if constexpr (DEPTH == 3){
        // ---- bn2 + relu -> hB ----
#pragma unroll
        for (int u = 0; u < 4; u++)
          sm[L::HB + row * 68 + grp * 4 + u] = fmaxf(fmaf(acc2[u], sa2[u], sb2[u]), 0.f);
        __syncthreads();

        // ---- mm3: y3[row][grp*8+u], W3 bf16 in LDS ----
        float acc3[8];
#pragma unroll
        for (int u = 0; u < 8; u++) acc3[u] = 0.f;
#pragma unroll 2
        for (int cb = 0; cb < 64; cb += 4){
          const float4 xv = *(const float4*)&sm[L::HB + row * 68 + cb];
#pragma unroll
          for (int u = 0; u < 8; u++){
            const uint2 wp = *(const uint2*)&w3p[(grp * 8 + u) * 64 + cb];
            acc3[u] = fmaf(xv.x, bflo(wp.x), acc3[u]);
            acc3[u] = fmaf(xv.y, bfhi(wp.x), acc3[u]);
            acc3[u] = fmaf(xv.z, bflo(wp.y), acc3[u]);
            acc3[u] = fmaf(xv.w, bfhi(wp.y), acc3[u]);
          }
        }
#pragma unroll
        for (int u = 0; u < 8; u++){ stS[u] += acc3[u]; stQ[u] = fmaf(acc3[u], acc3[u], stQ[u]); }

        // ---- pre-BN max/min over the 32 rows (lanes within half-wave) ----
        const int s = g & 1023;
#pragma unroll
        for (int u = 0; u < 8; u++){
          float mx = acc3[u], mn = acc3[u];
#pragma unroll
          for (int m = 1; m < 32; m <<= 1){
            mx = fmaxf(mx, __shfl_xor(mx, m));
            mn = fminf(mn, __shfl_xor(mn, m));
          }
          if (row == 0){
            size_t o = ((size_t)b * 128 + grp * 8 + u) * 1024 + s;
            m3max[o] = f2bf(mx); m3min[o] = f2bf(mn);
          }
        }
      }
    }
  }

  // ---- block stats partials: reduce over rows (half-wave lanes) ----
#pragma unroll
  for (int m = 1; m < 32; m <<= 1){
#pragma unroll
    for (int u = 0; u < US; u++){
      stS[u] += __shfl_xor(stS[u], m);
      stQ[u] += __shfl_xor(stQ[u], m);
    }
  }
  if (row == 0){
    constexpr int CH = (DEPTH == 3) ? 128 : 64;
    float* p = partials + (size_t)blockIdx.x * (2 * CH);
    const int o0 = grp * US;
#pragma unroll
    for (int u = 0; u < US; u++){ p[o0 + u] = stS[u]; p[CH + o0 + u] = stQ[u]; }
  }
}

// ---- stats stage 2: reduce 512 partial rows, emit per-channel scale/shift ----
template<int CH>
__global__ __launch_bounds__(256) void stats_fin(const float* __restrict__ partials,
                                                 const float* __restrict__ g,
                                                 const float* __restrict__ bet,
                                                 float* __restrict__ sab){
  const int t = threadIdx.x;
  __shared__ float red[2 * CH];
  if (t < 2 * CH){
    float a = 0.f;
#pragma unroll 8
    for (int r = 0; r < 512; r++) a += partials[(size_t)r * (2 * CH) + t];
    red[t] = a;
  }
  __syncthreads();
  if (t < CH){
    constexpr float inv = 1.f / (float)((size_t)B_ * S_ * K_);
    float mean = red[t] * inv;
    float var  = red[CH + t] * inv - mean * mean;
    float r    = 1.f / sqrtf(var + BN_EPS_);
    float a    = r * g[t];
    sab[t] = a;
    sab[CH + t] = bet[t] - mean * a;
  }
}

// ---- final: bn3(+relu) on bf16 pre-BN max/min (monotone-affine dispatch) ----
__global__ __launch_bounds__(256) void final_kernel(const unsigned short* __restrict__ m3max,
                                                    const unsigned short* __restrict__ m3min,
                                                    const float* __restrict__ sab3,
                                                    float* __restrict__ outNF){
  const int q = blockIdx.x * 256 + threadIdx.x;   // quad index over B*128*1024/4
  const int e = q * 4;
  const int o = (e >> 10) & 127;
  const float a = sab3[o], c = sab3[128 + o];
  const ushort4 mx = ((const ushort4*)m3max)[q];
  const ushort4 mn = ((const ushort4*)m3min)[q];
  float4 r;
  r.x = fmaxf(fmaf(bfu(a >= 0.f ? mx.x : mn.x), a, c), 0.f);
  r.y = fmaxf(fmaf(bfu(a >= 0.f ? mx.y : mn.y), a, c), 0.f);
  r.z = fmaxf(fmaf(bfu(a >= 0.f ? mx.z : mn.z), a, c), 0.f);
  r.w = fmaxf(fmaf(bfu(a >= 0.f ? mx.w : mn.w), a, c), 0.f);
  ((float4*)outNF)[q] = r;
}

extern "C" void kernel_launch(void* const* d_in, const int* in_sizes, int n_in,
                              void* d_out, int out_size, void* d_ws, size_t ws_size,
                              hipStream_t stream){
  (void)in_sizes; (void)n_in; (void)out_size;
  const float* xyz = (const float*)d_in[0];
  const float* feat = (const float*)d_in[1];
  const float* W1 = (const float*)d_in[2];
  const float* g1 = (const float*)d_in[3];
  const float* b1 = (const float*)d_in[4];
  const float* W2 = (const float*)d_in[5];
  const float* g2 = (const float*)d_in[6];
  const float* b2 = (const float*)d_in[7];
  const float* W3 = (const float*)d_in[8];
  const float* g3 = (const float*)d_in[9];
  const float* b3 = (const float*)d_in[10];

  float* newxyz = (float*)d_out;                       // (B,S,3)
  float* outNF  = newxyz + (size_t)B_ * S_ * 3;        // (B,128,S)
  char* ws = (char*)d_ws;

  size_t off = 0;
  auto alloc = [&](size_t bytes){ size_t o = off; off += (bytes + 255) & ~(size_t)255; return o; };
  size_t o_idx  = alloc((size_t)B_ * S_ * K_ * 4);           // 2 MB
  size_t o_part = alloc((size_t)512 * 256 * 4);              // 512 KB
  size_t o_sab1 = alloc(1024);
  size_t o_sab2 = alloc(1024);
  size_t o_sab3 = alloc(1024);
  size_t o_m3mx = alloc((size_t)B_ * S_ * 128 * 2);          // 4 MB (bf16)
  size_t o_m3mn = alloc((size_t)B_ * S_ * 128 * 2);          // 4 MB (bf16)
  size_t o_featT = alloc((size_t)B_ * N_ * C_ * 2);          // 8 MB (bf16)
  const bool ft = ws_size >= off;                            // 19.4 MB total

  int*   idxp  = (int*)(ws + o_idx);
  float* part  = (float*)(ws + o_part);
  float* sab1  = (float*)(ws + o_sab1);
  float* sab2  = (float*)(ws + o_sab2);
  float* sab3  = (float*)(ws + o_sab3);
  unsigned short* m3mx  = (unsigned short*)(ws + o_m3mx);
  unsigned short* m3mn  = (unsigned short*)(ws + o_m3mn);
  unsigned short* featT = (unsigned short*)(ws + o_featT);

  if (ft) transpose_kernel<<<dim3(N_ / 32, B_), dim3(32, 8), 0, stream>>>(feat, featT);
  fps_kernel<<<B_, 256, 0, stream>>>(xyz, newxyz);
  ballq_kernel<<<B_ * S_ / 4, 256, 0, stream>>>(xyz, newxyz, idxp);

  if (ft){
    pass_kernel<1, true><<<512, 512, 0, stream>>>(xyz, feat, featT, newxyz, idxp,
        W1, W2, W3, sab1, sab2, part, m3mx, m3mn);
    stats_fin<64><<<1, 256, 0, stream>>>(part, g1, b1, sab1);
    pass_kernel<2, true><<<512, 512, 0, stream>>>(xyz, feat, featT, newxyz, idxp,
        W1, W2, W3, sab1, sab2, part, m3mx, m3mn);
    stats_fin<64><<<1, 256, 0, stream>>>(part, g2, b2, sab2);
    pass_kernel<3, true><<<512, 512, 0, stream>>>(xyz, feat, featT, newxyz, idxp,
        W1, W2, W3, sab1, sab2, part, m3mx, m3mn);
    stats_fin<128><<<1, 256, 0, stream>>>(part, g3, b3, sab3);
  } else {
    pass_kernel<1, false><<<512, 512, 0, stream>>>(xyz, feat, featT, newxyz, idxp,
        W1, W2, W3, sab1, sab2, part, m3mx, m3mn);
    stats_fin<64><<<1, 256, 0, stream>>>(part, g1, b1, sab1);
    pass_kernel<2, false><<<512, 512, 0, stream>>>(xyz, feat, featT, newxyz, idxp,
        W1, W2, W3, sab1, sab2, part, m3mx, m3mn);
    stats_fin<64><<<1, 256, 0, stream>>>(part, g2, b2, sab2);
    pass_kernel<3, false><<<512, 512, 0, stream>>>(xyz, feat, featT, newxyz, idxp,
        W1, W2, W3, sab1, sab2, part, m3mx, m3mn);
    stats_fin<128><<<1, 256, 0, stream>>>(part, g3, b3, sab3);
  }
  final_kernel<<<(B_ * 128 * S_) / 1024, 256, 0, stream>>>(m3mx, m3mn, sab3, outNF);
}

// Round 14
// 1663.096 us; speedup vs baseline: 1.1302x; 1.0454x over previous
//
#include <hip/hip_runtime.h>
#include <hip/hip_bf16.h>

// ---- problem constants ----
static constexpr int B_ = 16;
static constexpr int N_ = 8192;
static constexpr int C_ = 32;     // input feature channels
static constexpr int S_ = 1024;   // NPOINT
static constexpr int K_ = 32;     // NSAMPLE
static constexpr float BN_EPS_ = 1e-5f;

typedef float f32x2 __attribute__((ext_vector_type(2)));

__device__ __forceinline__ unsigned short f2bf(float f){
  unsigned u = __float_as_uint(f);
  unsigned r = (u + 0x7fffu + ((u >> 16) & 1u)) >> 16;
  return (unsigned short)r;
}
__device__ __forceinline__ float bflo(unsigned u){ return __int_as_float(u << 16); }
__device__ __forceinline__ float bfhi(unsigned u){ return __int_as_float(u & 0xffff0000u); }
__device__ __forceinline__ float bfu(unsigned short u){ return __int_as_float(((unsigned)u) << 16); }

// rocPRIM-standard wave64 DPP reduce step on a u64 key (HW-proven R9/R10/R13).
template<int CTRL>
__device__ __forceinline__ unsigned long long dpp64(unsigned long long v){
  int lo = (int)(unsigned)(v & 0xffffffffull);
  int hi = (int)(unsigned)(v >> 32);
  int lo2 = __builtin_amdgcn_update_dpp(lo, lo, CTRL, 0xf, 0xf, false);
  int hi2 = __builtin_amdgcn_update_dpp(hi, hi, CTRL, 0xf, 0xf, false);
  return (((unsigned long long)(unsigned)hi2) << 32) | (unsigned)lo2;
}
__device__ __forceinline__ unsigned long long u64max(unsigned long long a,
                                                     unsigned long long b){
  return a > b ? a : b;
}

// ---- features (B,C,N) f32 -> featT (B,N,C) bf16 ----
__global__ __launch_bounds__(256) void transpose_kernel(const float* __restrict__ feat,
                                                        unsigned short* __restrict__ featT){
  __shared__ float tile[32][33];
  const int b = blockIdx.y;
  const int n0 = blockIdx.x * 32;
  const int tx = threadIdx.x, ty = threadIdx.y;
#pragma unroll
  for (int i = 0; i < 4; i++){
    int c = ty + i * 8;
    tile[c][tx] = feat[((size_t)b * C_ + c) * N_ + n0 + tx];
  }
  __syncthreads();
#pragma unroll
  for (int i = 0; i < 4; i++){
    int r = ty + i * 8;
    featT[((size_t)b * N_ + n0 + r) * C_ + tx] = f2bf(tile[tx][r]);
  }
}

// ---- furthest point sampling: 1 block/batch, 256 threads, 1 barrier/iter ----
// R13 HW-proven skeleton (plain-C f32x2 math, scalar pins, u64 key, DPP
// reduce, LDS-broadcast centroid, value-only tracking + descending scan).
// Single change vs R13: cross-wave combine via parity-double-buffered plain
// slot writes (R5-proven pattern) + per-thread 4-slot reduce — removes the 4
// serialized same-address LDS atomics and the slot-zeroing from the critical
// path. Writers write slots[p] pre-barrier; readers read slots[p]
// post-barrier; next iteration uses slots[p^1] -> no WAR hazard, 1 barrier.
__global__ __launch_bounds__(256) void fps_kernel(const float* __restrict__ xyz,
                                                  float* __restrict__ newxyz){
  const int b = blockIdx.x, t = threadIdx.x;      // t in [0,256)
  const float* px = xyz + (size_t)b * N_ * 3;
  __shared__ float pl[N_ * 3];                    // 96 KB copy of the batch
  __shared__ unsigned long long slots[2][4];      // [parity][wave]

  // coalesced global -> LDS copy
  for (int i = t; i < N_ * 3 / 4; i += 256)
    ((float4*)pl)[i] = ((const float4*)px)[i];

  f32x2 X2[16], Y2[16], Z2[16], MD2[16];
#pragma unroll
  for (int q = 0; q < 16; q++){
    const int p0 = 512 * q + t, p1 = 512 * q + 256 + t;
    float x0 = px[3 * p0 + 0], y0 = px[3 * p0 + 1], z0 = px[3 * p0 + 2];
    float x1 = px[3 * p1 + 0], y1 = px[3 * p1 + 1], z1 = px[3 * p1 + 2];
    asm volatile("" : "+v"(x0), "+v"(y0), "+v"(z0),
                      "+v"(x1), "+v"(y1), "+v"(z1));   // pin SCALARS in VGPRs
    X2[q] = f32x2{x0, x1};
    Y2[q] = f32x2{y0, y1};
    Z2[q] = f32x2{z0, z1};
    MD2[q] = f32x2{1e10f, 1e10f};
  }
  if (t == 0){
    size_t o = (size_t)b * S_ * 3;
    newxyz[o] = px[0]; newxyz[o + 1] = px[1]; newxyz[o + 2] = px[2];
  }
  float cx = px[0], cy = px[1], cz = px[2];
  __syncthreads();                                // covers pl copy

  for (int i = 1; i < S_; i++){
    const int p = i & 1;
    const f32x2 cx2 = {cx, cx}, cy2 = {cy, cy}, cz2 = {cz, cz};
    float tmax = -1.f;
#pragma unroll
    for (int q = 0; q < 16; q++){
      f32x2 dx = X2[q] - cx2;                     // per-half rn sub
      f32x2 dy = Y2[q] - cy2;
      f32x2 dz = Z2[q] - cz2;
      f32x2 dd = (dx * dx + dy * dy) + dz * dz;   // exact reference op order
      f32x2 m;
      m[0] = fminf(MD2[q][0], dd[0]);
      m[1] = fminf(MD2[q][1], dd[1]);
      MD2[q] = m;
      tmax = fmaxf(tmax, fmaxf(m[0], m[1]));      // v_max3-fusable
    }
    // recover this thread's FIRST (smallest global) index attaining tmax:
    // descending q, high half (bigger idx) before low half -> later (smaller)
    // assignments overwrite.
    unsigned cand = 0;
#pragma unroll
    for (int q = 15; q >= 0; q--){
      if (MD2[q][1] == tmax) cand = (unsigned)(512 * q + 256 + t);
      if (MD2[q][0] == tmax) cand = (unsigned)(512 * q + t);
    }
    // key: larger value wins; tie -> larger (8191-idx) -> smaller idx.
    unsigned long long key = ((unsigned long long)__float_as_uint(tmax) << 32)
                           | (unsigned long long)(8191u - cand);
    // wave64 DPP reduce -> lane 63 holds the wave max
    key = u64max(key, dpp64<0xb1>(key));          // quad_perm [1,0,3,2]
    key = u64max(key, dpp64<0x4e>(key));          // quad_perm [2,3,0,1]
    key = u64max(key, dpp64<0x114>(key));         // row_shr:4
    key = u64max(key, dpp64<0x118>(key));         // row_shr:8
    key = u64max(key, dpp64<0x142>(key));         // row_bcast:15
    key = u64max(key, dpp64<0x143>(key));         // row_bcast:31
    if ((t & 63) == 63) slots[p][t >> 6] = key;   // plain write, 1 per wave
    __syncthreads();
    // every thread reduces the 4 slots (parallel LDS reads, no atomics)
    unsigned long long best = u64max(u64max(slots[p][0], slots[p][1]),
                                     u64max(slots[p][2], slots[p][3]));
    const int fi = 8191 - (int)(best & 0xffffu);
    cx = pl[3 * fi]; cy = pl[3 * fi + 1]; cz = pl[3 * fi + 2];  // LDS broadcast
    if (t == 0){
      size_t o = ((size_t)b * S_ + i) * 3;
      newxyz[o] = cx; newxyz[o + 1] = cy; newxyz[o + 2] = cz;
    }
  }
}

// ---- ball query: 1 wave per centroid ----
__global__ __launch_bounds__(256) void ballq_kernel(const float* __restrict__ xyz,
                                                    const float* __restrict__ newxyz,
                                                    int* __restrict__ idxout){
  const int wave = threadIdx.x >> 6, lane = threadIdx.x & 63;
  const int cid = blockIdx.x * 4 + wave;
  const int b = cid >> 10;
  const float cx = newxyz[(size_t)cid * 3];
  const float cy = newxyz[(size_t)cid * 3 + 1];
  const float cz = newxyz[(size_t)cid * 3 + 2];
  const float* px = xyz + (size_t)b * N_ * 3;
  __shared__ int buf[4][32];
  const float r2 = 0.04f;   // fp32(double(0.2*0.2)) == 0x3D23D70A
  int have = 0;
  for (int base = 0; base < N_ && have < 32; base += 64){
    int p = base + lane;
    float dx = __fsub_rn(cx, px[3 * p]);
    float dy = __fsub_rn(cy, px[3 * p + 1]);
    float dz = __fsub_rn(cz, px[3 * p + 2]);
    float sq = __fadd_rn(__fadd_rn(__fmul_rn(dx, dx), __fmul_rn(dy, dy)), __fmul_rn(dz, dz));
    bool pred = sq < r2;
    unsigned long long m = __ballot(pred);
    if (pred){
      int pos = have + __popcll(m & ((1ull << lane) - 1ull));
      if (pos < 32) buf[wave][pos] = p;
    }
    have += (int)__popcll(m);
  }
  __syncthreads();
  if (lane < 32){
    int first = buf[wave][0];
    int v = (lane < have) ? buf[wave][lane] : first;
    idxout[(size_t)cid * 32 + lane] = v;
  }
}

// ---- LDS arena layout for the recompute pass kernels (all f32 now) ----
template<int DEPTH>
struct PassLds {
  static constexpr int XS  = 0;                 // [32][36] f32 (x tile, col35 zeroed)
  static constexpr int W1O = XS + 32 * 36;      // [64][36] f32 (col35 zeroed)
  static constexpr int HA  = W1O + 64 * 36;     // [32][68] f32 (DEPTH>=2)
  static constexpr int W2O = HA + 32 * 68;      // [64][64] f32
  static constexpr int HB  = W2O + 64 * 64;     // [32][68] f32 (DEPTH==3)
  static constexpr int W3O = HB + 32 * 68;      // [128][64] f32
  static constexpr int FLOATS = (DEPTH == 1) ? (W1O + 64 * 36)
                             : (DEPTH == 2) ? (W2O + 64 * 64)
                             : (W3O + 128 * 64);   // D3: 20096 floats = 80384 B
};

// ---- fused recompute pass (512 threads: row = t&31, grp = t>>5 in [0,16)) ----
template<int DEPTH, bool FT>
__global__ __launch_bounds__(512) void pass_kernel(
    const float* __restrict__ xyz, const float* __restrict__ feat,
    const unsigned short* __restrict__ featT, const float* __restrict__ newxyz,
    const int* __restrict__ idx,
    const float* __restrict__ W1, const float* __restrict__ W2,
    const float* __restrict__ W3,
    const float* __restrict__ sab1, const float* __restrict__ sab2,
    float* __restrict__ partials,
    unsigned short* __restrict__ m3max, unsigned short* __restrict__ m3min){
  using L = PassLds<DEPTH>;
  __shared__ float sm[L::FLOATS];
  const int t = threadIdx.x;
  const int row = t & 31, grp = t >> 5;   // sample-row, channel-group

  // ---- stage weights once per block ----
  for (int i = t; i < 64 * 36; i += 512){
    int o = i / 36, c = i - o * 36;
    sm[L::W1O + i] = (c < 35) ? W1[o * 35 + c] : 0.f;
  }
  if constexpr (DEPTH >= 2){
    for (int i = t; i < 64 * 64; i += 512) sm[L::W2O + i] = W2[i];
  }
  if constexpr (DEPTH == 3){
    for (int i = t; i < 128 * 64; i += 512) sm[L::W3O + i] = W3[i];
  }

  // ---- per-thread BN params ----
  float sa1[4], sb1[4], sa2[4], sb2[4];
  if constexpr (DEPTH >= 2){
#pragma unroll
    for (int u = 0; u < 4; u++){ sa1[u] = sab1[grp * 4 + u]; sb1[u] = sab1[64 + grp * 4 + u]; }
  }
  if constexpr (DEPTH == 3){
#pragma unroll
    for (int u = 0; u < 4; u++){ sa2[u] = sab2[grp * 4 + u]; sb2[u] = sab2[64 + grp * 4 + u]; }
  }

  constexpr int US = (DEPTH == 3) ? 8 : 4;     // stats channels per thread
  float stS[US], stQ[US];
#pragma unroll
  for (int u = 0; u < US; u++){ stS[u] = 0.f; stQ[u] = 0.f; }

  for (int it = 0; it < 32; ++it){
    const int g = blockIdx.x * 32 + it;
    const int b = g >> 10;
    if constexpr (DEPTH == 1) __syncthreads();  // protect XS from prev readers

    // ---- gather x tile: [32 pts][3 rel-coords | 32 feats | 0 pad] ----
    {
      float* xr = &sm[L::XS + row * 36];
      if constexpr (FT){
        if (grp < 4){
          const int id = idx[(size_t)g * 32 + row];
          const uint4 f = *(const uint4*)(featT + ((size_t)b * N_ + id) * C_ + grp * 8);
          xr[3 + grp * 8 + 0] = bflo(f.x); xr[3 + grp * 8 + 1] = bfhi(f.x);
          xr[3 + grp * 8 + 2] = bflo(f.y); xr[3 + grp * 8 + 3] = bfhi(f.y);
          xr[3 + grp * 8 + 4] = bflo(f.z); xr[3 + grp * 8 + 5] = bfhi(f.z);
          xr[3 + grp * 8 + 6] = bflo(f.w); xr[3 + grp * 8 + 7] = bfhi(f.w);
        } else if (grp == 4){
          const int id = idx[(size_t)g * 32 + row];
          size_t pb = ((size_t)b * N_ + id) * 3;
          xr[0] = __fsub_rn(xyz[pb + 0], newxyz[(size_t)g * 3 + 0]);
          xr[1] = __fsub_rn(xyz[pb + 1], newxyz[(size_t)g * 3 + 1]);
          xr[2] = __fsub_rn(xyz[pb + 2], newxyz[(size_t)g * 3 + 2]);
          xr[35] = 0.f;
        }
      } else {
        if (grp < 8){
          const int id = idx[(size_t)g * 32 + row];
#pragma unroll
          for (int q = 0; q < 4; q++)
            xr[3 + grp * 4 + q] = feat[((size_t)b * C_ + grp * 4 + q) * N_ + id];
        } else if (grp == 8){
          const int id = idx[(size_t)g * 32 + row];
          size_t pb = ((size_t)b * N_ + id) * 3;
          xr[0] = __fsub_rn(xyz[pb + 0], newxyz[(size_t)g * 3 + 0]);
          xr[1] = __fsub_rn(xyz[pb + 1], newxyz[(size_t)g * 3 + 1]);
          xr[2] = __fsub_rn(xyz[pb + 2], newxyz[(size_t)g * 3 + 2]);
          xr[35] = 0.f;
        }
      }
    }
    __syncthreads();

    // ---- mm1: y1[row][grp*4+u] ----
    float acc[4] = {0.f, 0.f, 0.f, 0.f};
#pragma unroll 3
    for (int cb = 0; cb < 36; cb += 4){
      const float4 xv = *(const float4*)&sm[L::XS + row * 36 + cb];
#pragma unroll
      for (int u = 0; u < 4; u++){
        const float4 wv = *(const float4*)&sm[L::W1O + (grp * 4 + u) * 36 + cb];
        acc[u] = fmaf(xv.x, wv.x, acc[u]);
        acc[u] = fmaf(xv.y, wv.y, acc[u]);
        acc[u] = fmaf(xv.z, wv.z, acc[u]);
        acc[u] = fmaf(xv.w, wv.w, acc[u]);
      }
    }
    if constexpr (DEPTH == 1){
#pragma unroll
      for (int u = 0; u < 4; u++){ stS[u] += acc[u]; stQ[u] = fmaf(acc[u], acc[u], stQ[u]); }
      continue;
    }

    if constexpr (DEPTH >= 2){
      // ---- bn1 + relu -> hA ----
#pragma unroll
      for (int u = 0; u < 4; u++)
        sm[L::HA + row * 68 + grp * 4 + u] = fmaxf(fmaf(acc[u], sa1[u], sb1[u]), 0.f);
      __syncthreads();

      // ---- mm2 ----
      float acc2[4] = {0.f, 0.f, 0.f, 0.f};
#pragma unroll 4
      for (int cb = 0; cb < 64; cb += 4){
        const float4 xv = *(const float4*)&sm[L::HA + row * 68 + cb];
#pragma unroll
        for (int u = 0; u < 4; u++){
          const float4 wv = *(const float4*)&sm[L::W2O + (grp * 4 + u) * 64 + cb];
          acc2[u] = fmaf(xv.x, wv.x, acc2[u]);
          acc2[u] = fmaf(xv.y, wv.y, acc2[u]);
          acc2[u] = fmaf(xv.z, wv.z, acc2[u]);
          acc2[u] = fmaf(xv.w, wv.w, acc2[u]);
        }
      }
      if constexpr (DEPTH == 2){
#pragma unroll
        for (int u = 0; u < 4; u++){ stS[u] += acc2[u]; stQ[u] = fmaf(acc2[u], acc2[u], stQ[u]); }
        continue;
      }

      if constexpr (DEPTH == 3){
        // ---- bn2 + relu -> hB ----
#pragma unroll
        for (int u = 0; u < 4; u++)
          sm[L::HB + row * 68 + grp * 4 + u] = fmaxf(fmaf(acc2[u], sa2[u], sb2[u]), 0.f);
        __syncthreads();

        // ---- mm3: y3[row][grp*8+u], W3 f32 in LDS (no unpack ops) ----
        float acc3[8];
#pragma unroll
        for (int u = 0; u < 8; u++) acc3[u] = 0.f;
#pragma unroll 2
        for (int cb = 0; cb < 64; cb += 4){
          const float4 xv = *(const float4*)&sm[L::HB + row * 68 + cb];
#pragma unroll
          for (int u = 0; u < 8; u++){
            const float4 wv = *(const float4*)&sm[L::W3O + (grp * 8 + u) * 64 + cb];
            acc3[u] = fmaf(xv.x, wv.x, acc3[u]);
            acc3[u] = fmaf(xv.y, wv.y, acc3[u]);
            acc3[u] = fmaf(xv.z, wv.z, acc3[u]);
            acc3[u] = fmaf(xv.w, wv.w, acc3[u]);
          }
        }
#pragma unroll
        for (int u = 0; u < 8; u++){ stS[u] += acc3[u]; stQ[u] = fmaf(acc3[u], acc3[u], stQ[u]); }

        // ---- pre-BN max/min over the 32 rows (lanes within half-wave) ----
        const int s = g & 1023;
#pragma unroll
        for (int u = 0; u < 8; u++){
          float mx = acc3[u], mn = acc3[u];
#pragma unroll
          for (int m = 1; m < 32; m <<= 1){
            mx = fmaxf(mx, __shfl_xor(mx, m));
            mn = fminf(mn, __shfl_xor(mn, m));
          }
          if (row == 0){
            size_t o = ((size_t)b * 128 + grp * 8 + u) * 1024 + s;
            m3max[o] = f2bf(mx); m3min[o] = f2bf(mn);
          }
        }
      }
    }
  }

  // ---- block stats partials: reduce over rows (half-wave lanes) ----
#pragma unroll
  for (int m = 1; m < 32; m <<= 1){
#pragma unroll
    for (int u = 0; u < US; u++){
      stS[u] += __shfl_xor(stS[u], m);
      stQ[u] += __shfl_xor(stQ[u], m);
    }
  }
  if (row == 0){
    constexpr int CH = (DEPTH == 3) ? 128 : 64;
    float* p = partials + (size_t)blockIdx.x * (2 * CH);
    const int o0 = grp * US;
#pragma unroll
    for (int u = 0; u < US; u++){ p[o0 + u] = stS[u]; p[CH + o0 + u] = stQ[u]; }
  }
}

// ---- stats stage 2: reduce 512 partial rows, emit per-channel scale/shift ----
template<int CH>
__global__ __launch_bounds__(256) void stats_fin(const float* __restrict__ partials,
                                                 const float* __restrict__ g,
                                                 const float* __restrict__ bet,
                                                 float* __restrict__ sab){
  const int t = threadIdx.x;
  __shared__ float red[2 * CH];
  if (t < 2 * CH){
    float a = 0.f;
#pragma unroll 8
    for (int r = 0; r < 512; r++) a += partials[(size_t)r * (2 * CH) + t];
    red[t] = a;
  }
  __syncthreads();
  if (t < CH){
    constexpr float inv = 1.f / (float)((size_t)B_ * S_ * K_);
    float mean = red[t] * inv;
    float var  = red[CH + t] * inv - mean * mean;
    float r    = 1.f / sqrtf(var + BN_EPS_);
    float a    = r * g[t];
    sab[t] = a;
    sab[CH + t] = bet[t] - mean * a;
  }
}

// ---- final: bn3(+relu) on bf16 pre-BN max/min (monotone-affine dispatch) ----
__global__ __launch_bounds__(256) void final_kernel(const unsigned short* __restrict__ m3max,
                                                    const unsigned short* __restrict__ m3min,
                                                    const float* __restrict__ sab3,
                                                    float* __restrict__ outNF){
  const int q = blockIdx.x * 256 + threadIdx.x;   // quad index over B*128*1024/4
  const int e = q * 4;
  const int o = (e >> 10) & 127;
  const float a = sab3[o], c = sab3[128 + o];
  const ushort4 mx = ((const ushort4*)m3max)[q];
  const ushort4 mn = ((const ushort4*)m3min)[q];
  float4 r;
  r.x = fmaxf(fmaf(bfu(a >= 0.f ? mx.x : mn.x), a, c), 0.f);
  r.y = fmaxf(fmaf(bfu(a >= 0.f ? mx.y : mn.y), a, c), 0.f);
  r.z = fmaxf(fmaf(bfu(a >= 0.f ? mx.z : mn.z), a, c), 0.f);
  r.w = fmaxf(fmaf(bfu(a >= 0.f ? mx.w : mn.w), a, c), 0.f);
  ((float4*)outNF)[q] = r;
}

extern "C" void kernel_launch(void* const* d_in, const int* in_sizes, int n_in,
                              void* d_out, int out_size, void* d_ws, size_t ws_size,
                              hipStream_t stream){
  (void)in_sizes; (void)n_in; (void)out_size;
  const float* xyz = (const float*)d_in[0];
  const float* feat = (const float*)d_in[1];
  const float* W1 = (const float*)d_in[2];
  const float* g1 = (const float*)d_in[3];
  const float* b1 = (const float*)d_in[4];
  const float* W2 = (const float*)d_in[5];
  const float* g2 = (const float*)d_in[6];
  const float* b2 = (const float*)d_in[7];
  const float* W3 = (const float*)d_in[8];
  const float* g3 = (const float*)d_in[9];
  const float* b3 = (const float*)d_in[10];

  float* newxyz = (float*)d_out;                       // (B,S,3)
  float* outNF  = newxyz + (size_t)B_ * S_ * 3;        // (B,128,S)
  char* ws = (char*)d_ws;

  size_t off = 0;
  auto alloc = [&](size_t bytes){ size_t o = off; off += (bytes + 255) & ~(size_t)255; return o; };
  size_t o_idx  = alloc((size_t)B_ * S_ * K_ * 4);           // 2 MB
  size_t o_part = alloc((size_t)512 * 256 * 4);              // 512 KB
  size_t o_sab1 = alloc(1024);
  size_t o_sab2 = alloc(1024);
  size_t o_sab3 = alloc(1024);
  size_t o_m3mx = alloc((size_t)B_ * S_ * 128 * 2);          // 4 MB (bf16)
  size_t o_m3mn = alloc((size_t)B_ * S_ * 128 * 2);          // 4 MB (bf16)
  size_t o_featT = alloc((size_t)B_ * N_ * C_ * 2);          // 8 MB (bf16)
  const bool ft = ws_size >= off;                            // 19.4 MB total

  int*   idxp  = (int*)(ws + o_idx);
  float* part  = (float*)(ws + o_part);
  float* sab1  = (float*)(ws + o_sab1);
  float* sab2  = (float*)(ws + o_sab2);
  float* sab3  = (float*)(ws + o_sab3);
  unsigned short* m3mx  = (unsigned short*)(ws + o_m3mx);
  unsigned short* m3mn  = (unsigned short*)(ws + o_m3mn);
  unsigned short* featT = (unsigned short*)(ws + o_featT);

  if (ft) transpose_kernel<<<dim3(N_ / 32, B_), dim3(32, 8), 0, stream>>>(feat, featT);
  fps_kernel<<<B_, 256, 0, stream>>>(xyz, newxyz);
  ballq_kernel<<<B_ * S_ / 4, 256, 0, stream>>>(xyz, newxyz, idxp);

  if (ft){
    pass_kernel<1, true><<<512, 512, 0, stream>>>(xyz, feat, featT, newxyz, idxp,
        W1, W2, W3, sab1, sab2, part, m3mx, m3mn);
    stats_fin<64><<<1, 256, 0, stream>>>(part, g1, b1, sab1);
    pass_kernel<2, true><<<512, 512, 0, stream>>>(xyz, feat, featT, newxyz, idxp,
        W1, W2, W3, sab1, sab2, part, m3mx, m3mn);
    stats_fin<64><<<1, 256, 0, stream>>>(part, g2, b2, sab2);
    pass_kernel<3, true><<<512, 512, 0, stream>>>(xyz, feat, featT, newxyz, idxp,
        W1, W2, W3, sab1, sab2, part, m3mx, m3mn);
    stats_fin<128><<<1, 256, 0, stream>>>(part, g3, b3, sab3);
  } else {
    pass_kernel<1, false><<<512, 512, 0, stream>>>(xyz, feat, featT, newxyz, idxp,
        W1, W2, W3, sab1, sab2, part, m3mx, m3mn);
    stats_fin<64><<<1, 256, 0, stream>>>(part, g1, b1, sab1);
    pass_kernel<2, false><<<512, 512, 0, stream>>>(xyz, feat, featT, newxyz, idxp,
        W1, W2, W3, sab1, sab2, part, m3mx, m3mn);
    stats_fin<64><<<1, 256, 0, stream>>>(part, g2, b2, sab2);
    pass_kernel<3, false><<<512, 512, 0, stream>>>(xyz, feat, featT, newxyz, idxp,
        W1, W2, W3, sab1, sab2, part, m3mx, m3mn);
    stats_fin<128><<<1, 256, 0, stream>>>(part, g3, b3, sab3);
  }
  final_kernel<<<(B_ * 128 * S_) / 1024, 256, 0, stream>>>(m3mx, m3mn, sab3, outNF);
}

// Round 15
// 1662.317 us; speedup vs baseline: 1.1307x; 1.0005x over previous
//
#include <hip/hip_runtime.h>
#include <hip/hip_bf16.h>

// ---- problem constants ----
static constexpr int B_ = 16;
static constexpr int N_ = 8192;
static constexpr int C_ = 32;     // input feature channels
static constexpr int S_ = 1024;   // NPOINT
static constexpr int K_ = 32;     // NSAMPLE
static constexpr float BN_EPS_ = 1e-5f;

typedef float f32x2 __attribute__((ext_vector_type(2)));

__device__ __forceinline__ unsigned short f2bf(float f){
  unsigned u = __float_as_uint(f);
  unsigned r = (u + 0x7fffu + ((u >> 16) & 1u)) >> 16;
  return (unsigned short)r;
}
__device__ __forceinline__ float bflo(unsigned u){ return __int_as_float(u << 16); }
__device__ __forceinline__ float bfhi(unsigned u){ return __int_as_float(u & 0xffff0000u); }
__device__ __forceinline__ float bfu(unsigned short u){ return __int_as_float(((unsigned)u) << 16); }

// rocPRIM-standard wave64 DPP reduce step on a u64 key (HW-proven R9/R10/R13/R14).
template<int CTRL>
__device__ __forceinline__ unsigned long long dpp64(unsigned long long v){
  int lo = (int)(unsigned)(v & 0xffffffffull);
  int hi = (int)(unsigned)(v >> 32);
  int lo2 = __builtin_amdgcn_update_dpp(lo, lo, CTRL, 0xf, 0xf, false);
  int hi2 = __builtin_amdgcn_update_dpp(hi, hi, CTRL, 0xf, 0xf, false);
  return (((unsigned long long)(unsigned)hi2) << 32) | (unsigned)lo2;
}
__device__ __forceinline__ unsigned long long u64max(unsigned long long a,
                                                     unsigned long long b){
  return a > b ? a : b;
}

// ---- features (B,C,N) f32 -> featT (B,N,C) bf16 ----
__global__ __launch_bounds__(256) void transpose_kernel(const float* __restrict__ feat,
                                                        unsigned short* __restrict__ featT){
  __shared__ float tile[32][33];
  const int b = blockIdx.y;
  const int n0 = blockIdx.x * 32;
  const int tx = threadIdx.x, ty = threadIdx.y;
#pragma unroll
  for (int i = 0; i < 4; i++){
    int c = ty + i * 8;
    tile[c][tx] = feat[((size_t)b * C_ + c) * N_ + n0 + tx];
  }
  __syncthreads();
#pragma unroll
  for (int i = 0; i < 4; i++){
    int r = ty + i * 8;
    featT[((size_t)b * N_ + n0 + r) * C_ + tx] = f2bf(tile[tx][r]);
  }
}

// ---- furthest point sampling: 1 block/batch, 256 threads, 1 barrier/iter ----
// R14 HW-proven version, unchanged (881 us, plateaued).
__global__ __launch_bounds__(256) void fps_kernel(const float* __restrict__ xyz,
                                                  float* __restrict__ newxyz){
  const int b = blockIdx.x, t = threadIdx.x;      // t in [0,256)
  const float* px = xyz + (size_t)b * N_ * 3;
  __shared__ float pl[N_ * 3];                    // 96 KB copy of the batch
  __shared__ unsigned long long slots[2][4];      // [parity][wave]

  // coalesced global -> LDS copy
  for (int i = t; i < N_ * 3 / 4; i += 256)
    ((float4*)pl)[i] = ((const float4*)px)[i];

  f32x2 X2[16], Y2[16], Z2[16], MD2[16];
#pragma unroll
  for (int q = 0; q < 16; q++){
    const int p0 = 512 * q + t, p1 = 512 * q + 256 + t;
    float x0 = px[3 * p0 + 0], y0 = px[3 * p0 + 1], z0 = px[3 * p0 + 2];
    float x1 = px[3 * p1 + 0], y1 = px[3 * p1 + 1], z1 = px[3 * p1 + 2];
    asm volatile("" : "+v"(x0), "+v"(y0), "+v"(z0),
                      "+v"(x1), "+v"(y1), "+v"(z1));   // pin SCALARS in VGPRs
    X2[q] = f32x2{x0, x1};
    Y2[q] = f32x2{y0, y1};
    Z2[q] = f32x2{z0, z1};
    MD2[q] = f32x2{1e10f, 1e10f};
  }
  if (t == 0){
    size_t o = (size_t)b * S_ * 3;
    newxyz[o] = px[0]; newxyz[o + 1] = px[1]; newxyz[o + 2] = px[2];
  }
  float cx = px[0], cy = px[1], cz = px[2];
  __syncthreads();                                // covers pl copy

  for (int i = 1; i < S_; i++){
    const int p = i & 1;
    const f32x2 cx2 = {cx, cx}, cy2 = {cy, cy}, cz2 = {cz, cz};
    float tmax = -1.f;
#pragma unroll
    for (int q = 0; q < 16; q++){
      f32x2 dx = X2[q] - cx2;                     // per-half rn sub
      f32x2 dy = Y2[q] - cy2;
      f32x2 dz = Z2[q] - cz2;
      f32x2 dd = (dx * dx + dy * dy) + dz * dz;   // exact reference op order
      f32x2 m;
      m[0] = fminf(MD2[q][0], dd[0]);
      m[1] = fminf(MD2[q][1], dd[1]);
      MD2[q] = m;
      tmax = fmaxf(tmax, fmaxf(m[0], m[1]));      // v_max3-fusable
    }
    unsigned cand = 0;
#pragma unroll
    for (int q = 15; q >= 0; q--){
      if (MD2[q][1] == tmax) cand = (unsigned)(512 * q + 256 + t);
      if (MD2[q][0] == tmax) cand = (unsigned)(512 * q + t);
    }
    unsigned long long key = ((unsigned long long)__float_as_uint(tmax) << 32)
                           | (unsigned long long)(8191u - cand);
    key = u64max(key, dpp64<0xb1>(key));          // quad_perm [1,0,3,2]
    key = u64max(key, dpp64<0x4e>(key));          // quad_perm [2,3,0,1]
    key = u64max(key, dpp64<0x114>(key));         // row_shr:4
    key = u64max(key, dpp64<0x118>(key));         // row_shr:8
    key = u64max(key, dpp64<0x142>(key));         // row_bcast:15
    key = u64max(key, dpp64<0x143>(key));         // row_bcast:31
    if ((t & 63) == 63) slots[p][t >> 6] = key;   // plain write, 1 per wave
    __syncthreads();
    unsigned long long best = u64max(u64max(slots[p][0], slots[p][1]),
                                     u64max(slots[p][2], slots[p][3]));
    const int fi = 8191 - (int)(best & 0xffffu);
    cx = pl[3 * fi]; cy = pl[3 * fi + 1]; cz = pl[3 * fi + 2];  // LDS broadcast
    if (t == 0){
      size_t o = ((size_t)b * S_ + i) * 3;
      newxyz[o] = cx; newxyz[o + 1] = cy; newxyz[o + 2] = cz;
    }
  }
}

// ---- ball query: 1 wave per centroid ----
__global__ __launch_bounds__(256) void ballq_kernel(const float* __restrict__ xyz,
                                                    const float* __restrict__ newxyz,
                                                    int* __restrict__ idxout){
  const int wave = threadIdx.x >> 6, lane = threadIdx.x & 63;
  const int cid = blockIdx.x * 4 + wave;
  const int b = cid >> 10;
  const float cx = newxyz[(size_t)cid * 3];
  const float cy = newxyz[(size_t)cid * 3 + 1];
  const float cz = newxyz[(size_t)cid * 3 + 2];
  const float* px = xyz + (size_t)b * N_ * 3;
  __shared__ int buf[4][32];
  const float r2 = 0.04f;   // fp32(double(0.2*0.2)) == 0x3D23D70A
  int have = 0;
  for (int base = 0; base < N_ && have < 32; base += 64){
    int p = base + lane;
    float dx = __fsub_rn(cx, px[3 * p]);
    float dy = __fsub_rn(cy, px[3 * p + 1]);
    float dz = __fsub_rn(cz, px[3 * p + 2]);
    float sq = __fadd_rn(__fadd_rn(__fmul_rn(dx, dx), __fmul_rn(dy, dy)), __fmul_rn(dz, dz));
    bool pred = sq < r2;
    unsigned long long m = __ballot(pred);
    if (pred){
      int pos = have + __popcll(m & ((1ull << lane) - 1ull));
      if (pos < 32) buf[wave][pos] = p;
    }
    have += (int)__popcll(m);
  }
  __syncthreads();
  if (lane < 32){
    int first = buf[wave][0];
    int v = (lane < have) ? buf[wave][lane] : first;
    idxout[(size_t)cid * 32 + lane] = v;
  }
}

// ---- LDS arena layout for the recompute pass kernels (all f32) ----
template<int DEPTH>
struct PassLds {
  static constexpr int XS  = 0;                 // [32][36] f32 (x tile, col35 zeroed)
  static constexpr int W1O = XS + 32 * 36;      // [64][36] f32 (col35 zeroed)
  static constexpr int HA  = W1O + 64 * 36;     // [32][68] f32 (DEPTH>=2)
  static constexpr int W2O = HA + 32 * 68;      // [64][64] f32
  static constexpr int HB  = W2O + 64 * 64;     // [32][68] f32 (DEPTH==3)
  static constexpr int W3O = HB + 32 * 68;      // [128][64] f32
  static constexpr int FLOATS = (DEPTH == 1) ? (W1O + 64 * 36)
                             : (DEPTH == 2) ? (W2O + 64 * 64)
                             : (W3O + 128 * 64);   // D3: 20096 floats = 80384 B
};

// ---- fused recompute pass (512 threads: row = t&31, grp = t>>5 in [0,16)) ----
// R14 math, now with T14-style pipelined gather: group it+1's idx/featT/xyz
// loads issue at the top of iteration it (registers), and commit to the xs
// tile right after the HA barrier (xs provably dead there). The HB/trailing
// barrier orders the commit against the next iteration's mm1. Barriers/iter:
// depth3 3->2, depth1/2 unchanged. __launch_bounds__(512,4) keeps VGPR<=128
// so 2 blocks/CU (16 waves) survive the extra prefetch registers.
template<int DEPTH, bool FT>
__global__ __launch_bounds__(512, 4) void pass_kernel(
    const float* __restrict__ xyz, const float* __restrict__ feat,
    const unsigned short* __restrict__ featT, const float* __restrict__ newxyz,
    const int* __restrict__ idx,
    const float* __restrict__ W1, const float* __restrict__ W2,
    const float* __restrict__ W3,
    const float* __restrict__ sab1, const float* __restrict__ sab2,
    float* __restrict__ partials,
    unsigned short* __restrict__ m3max, unsigned short* __restrict__ m3min){
  using L = PassLds<DEPTH>;
  __shared__ float sm[L::FLOATS];
  const int t = threadIdx.x;
  const int row = t & 31, grp = t >> 5;   // sample-row, channel-group

  // ---- stage weights once per block ----
  for (int i = t; i < 64 * 36; i += 512){
    int o = i / 36, c = i - o * 36;
    sm[L::W1O + i] = (c < 35) ? W1[o * 35 + c] : 0.f;
  }
  if constexpr (DEPTH >= 2){
    for (int i = t; i < 64 * 64; i += 512) sm[L::W2O + i] = W2[i];
  }
  if constexpr (DEPTH == 3){
    for (int i = t; i < 128 * 64; i += 512) sm[L::W3O + i] = W3[i];
  }

  // ---- per-thread BN params ----
  float sa1[4], sb1[4], sa2[4], sb2[4];
  if constexpr (DEPTH >= 2){
#pragma unroll
    for (int u = 0; u < 4; u++){ sa1[u] = sab1[grp * 4 + u]; sb1[u] = sab1[64 + grp * 4 + u]; }
  }
  if constexpr (DEPTH == 3){
#pragma unroll
    for (int u = 0; u < 4; u++){ sa2[u] = sab2[grp * 4 + u]; sb2[u] = sab2[64 + grp * 4 + u]; }
  }

  constexpr int US = (DEPTH == 3) ? 8 : 4;     // stats channels per thread
  float stS[US], stQ[US];
#pragma unroll
  for (int u = 0; u < US; u++){ stS[u] = 0.f; stQ[u] = 0.f; }

  // ---- prefetch state (registers) ----
  uint4 pfeat = {0, 0, 0, 0};                   // FT, grp<4
  float pf0 = 0.f, pf1 = 0.f, pf2 = 0.f, pf3 = 0.f;   // non-FT, grp<8
  float prx = 0.f, pry = 0.f, prz = 0.f;        // rel coords

  auto prefetch = [&](int it2){
    const int g2 = blockIdx.x * 32 + it2;
    const int b2 = g2 >> 10;
    if constexpr (FT){
      if (grp < 4){
        const int id = idx[(size_t)g2 * 32 + row];
        pfeat = *(const uint4*)(featT + ((size_t)b2 * N_ + id) * C_ + grp * 8);
      } else if (grp == 4){
        const int id = idx[(size_t)g2 * 32 + row];
        size_t pb = ((size_t)b2 * N_ + id) * 3;
        prx = __fsub_rn(xyz[pb + 0], newxyz[(size_t)g2 * 3 + 0]);
        pry = __fsub_rn(xyz[pb + 1], newxyz[(size_t)g2 * 3 + 1]);
        prz = __fsub_rn(xyz[pb + 2], newxyz[(size_t)g2 * 3 + 2]);
      }
    } else {
      if (grp < 8){
        const int id = idx[(size_t)g2 * 32 + row];
        pf0 = feat[((size_t)b2 * C_ + grp * 4 + 0) * N_ + id];
        pf1 = feat[((size_t)b2 * C_ + grp * 4 + 1) * N_ + id];
        pf2 = feat[((size_t)b2 * C_ + grp * 4 + 2) * N_ + id];
        pf3 = feat[((size_t)b2 * C_ + grp * 4 + 3) * N_ + id];
      } else if (grp == 8){
        const int id = idx[(size_t)g2 * 32 + row];
        size_t pb = ((size_t)b2 * N_ + id) * 3;
        prx = __fsub_rn(xyz[pb + 0], newxyz[(size_t)g2 * 3 + 0]);
        pry = __fsub_rn(xyz[pb + 1], newxyz[(size_t)g2 * 3 + 1]);
        prz = __fsub_rn(xyz[pb + 2], newxyz[(size_t)g2 * 3 + 2]);
      }
    }
  };
  auto commit_xs = [&](){
    float* xr = &sm[L::XS + row * 36];
    if constexpr (FT){
      if (grp < 4){
        xr[3 + grp * 8 + 0] = bflo(pfeat.x); xr[3 + grp * 8 + 1] = bfhi(pfeat.x);
        xr[3 + grp * 8 + 2] = bflo(pfeat.y); xr[3 + grp * 8 + 3] = bfhi(pfeat.y);
        xr[3 + grp * 8 + 4] = bflo(pfeat.z); xr[3 + grp * 8 + 5] = bfhi(pfeat.z);
        xr[3 + grp * 8 + 6] = bflo(pfeat.w); xr[3 + grp * 8 + 7] = bfhi(pfeat.w);
      } else if (grp == 4){
        xr[0] = prx; xr[1] = pry; xr[2] = prz; xr[35] = 0.f;
      }
    } else {
      if (grp < 8){
        xr[3 + grp * 4 + 0] = pf0; xr[3 + grp * 4 + 1] = pf1;
        xr[3 + grp * 4 + 2] = pf2; xr[3 + grp * 4 + 3] = pf3;
      } else if (grp == 8){
        xr[0] = prx; xr[1] = pry; xr[2] = prz; xr[35] = 0.f;
      }
    }
  };

  prefetch(0);
  commit_xs();
  __syncthreads();    // covers weights + xs(0)

  for (int it = 0; it < 32; ++it){
    const int g = blockIdx.x * 32 + it;
    const int b = g >> 10;
    if (it < 31) prefetch(it + 1);              // issue next group's loads

    // ---- mm1: y1[row][grp*4+u] (reads xs) ----
    float acc[4] = {0.f, 0.f, 0.f, 0.f};
#pragma unroll 3
    for (int cb = 0; cb < 36; cb += 4){
      const float4 xv = *(const float4*)&sm[L::XS + row * 36 + cb];
#pragma unroll
      for (int u = 0; u < 4; u++){
        const float4 wv = *(const float4*)&sm[L::W1O + (grp * 4 + u) * 36 + cb];
        acc[u] = fmaf(xv.x, wv.x, acc[u]);
        acc[u] = fmaf(xv.y, wv.y, acc[u]);
        acc[u] = fmaf(xv.z, wv.z, acc[u]);
        acc[u] = fmaf(xv.w, wv.w, acc[u]);
      }
    }
    if constexpr (DEPTH == 1){
#pragma unroll
      for (int u = 0; u < 4; u++){ stS[u] += acc[u]; stQ[u] = fmaf(acc[u], acc[u], stQ[u]); }
      __syncthreads();                          // all mm1 reads of xs done
      if (it < 31) commit_xs();
      __syncthreads();                          // xs(it+1) visible
      continue;
    }

    // ---- bn1 + relu -> hA ----
#pragma unroll
    for (int u = 0; u < 4; u++)
      sm[L::HA + row * 68 + grp * 4 + u] = fmaxf(fmaf(acc[u], sa1[u], sb1[u]), 0.f);
    __syncthreads();                            // HA ready; xs dead
    if (it < 31) commit_xs();                   // overlap with mm2/mm3

    // ---- mm2 ----
    float acc2[4] = {0.f, 0.f, 0.f, 0.f};
#pragma unroll 4
    for (int cb = 0; cb < 64; cb += 4){
      const float4 xv = *(const float4*)&sm[L::HA + row * 68 + cb];
#pragma unroll
      for (int u = 0; u < 4; u++){
        const float4 wv = *(const float4*)&sm[L::W2O + (grp * 4 + u) * 64 + cb];
        acc2[u] = fmaf(xv.x, wv.x, acc2[u]);
        acc2[u] = fmaf(xv.y, wv.y, acc2[u]);
        acc2[u] = fmaf(xv.z, wv.z, acc2[u]);
        acc2[u] = fmaf(xv.w, wv.w, acc2[u]);
      }
    }
    if constexpr (DEPTH == 2){
#pragma unroll
      for (int u = 0; u < 4; u++){ stS[u] += acc2[u]; stQ[u] = fmaf(acc2[u], acc2[u], stQ[u]); }
      __syncthreads();                          // orders xs commit + HA reuse
      continue;
    }

    if constexpr (DEPTH == 3){
      // ---- bn2 + relu -> hB ----
#pragma unroll
      for (int u = 0; u < 4; u++)
        sm[L::HB + row * 68 + grp * 4 + u] = fmaxf(fmaf(acc2[u], sa2[u], sb2[u]), 0.f);
      __syncthreads();                          // HB ready; xs commit visible

      // ---- mm3: y3[row][grp*8+u], W3 f32 in LDS ----
      float acc3[8];
#pragma unroll
      for (int u = 0; u < 8; u++) acc3[u] = 0.f;
#pragma unroll 2
      for (int cb = 0; cb < 64; cb += 4){
        const float4 xv = *(const float4*)&sm[L::HB + row * 68 + cb];
#pragma unroll
        for (int u = 0; u < 8; u++){
          const float4 wv = *(const float4*)&sm[L::W3O + (grp * 8 + u) * 64 + cb];
          acc3[u] = fmaf(xv.x, wv.x, acc3[u]);
          acc3[u] = fmaf(xv.y, wv.y, acc3[u]);
          acc3[u] = fmaf(xv.z, wv.z, acc3[u]);
          acc3[u] = fmaf(xv.w, wv.w, acc3[u]);
        }
      }
#pragma unroll
      for (int u = 0; u < 8; u++){ stS[u] += acc3[u]; stQ[u] = fmaf(acc3[u], acc3[u], stQ[u]); }

      // ---- pre-BN max/min over the 32 rows (lanes within half-wave) ----
      const int s = g & 1023;
#pragma unroll
      for (int u = 0; u < 8; u++){
        float mx = acc3[u], mn = acc3[u];
#pragma unroll
        for (int m = 1; m < 32; m <<= 1){
          mx = fmaxf(mx, __shfl_xor(mx, m));
          mn = fminf(mn, __shfl_xor(mn, m));
        }
        if (row == 0){
          size_t o = ((size_t)b * 128 + grp * 8 + u) * 1024 + s;
          m3max[o] = f2bf(mx); m3min[o] = f2bf(mn);
        }
      }
      // next iteration's mm1 reads xs(it+1): HB barrier above already
      // separated commit_xs from those reads; bn1(it+1)'s HA writes are
      // separated from this iteration's mm2 HA reads by the next HA barrier.
    }
  }

  // ---- block stats partials: reduce over rows (half-wave lanes) ----
#pragma unroll
  for (int m = 1; m < 32; m <<= 1){
#pragma unroll
    for (int u = 0; u < US; u++){
      stS[u] += __shfl_xor(stS[u], m);
      stQ[u] += __shfl_xor(stQ[u], m);
    }
  }
  if (row == 0){
    constexpr int CH = (DEPTH == 3) ? 128 : 64;
    float* p = partials + (size_t)blockIdx.x * (2 * CH);
    const int o0 = grp * US;
#pragma unroll
    for (int u = 0; u < US; u++){ p[o0 + u] = stS[u]; p[CH + o0 + u] = stQ[u]; }
  }
}

// ---- stats stage 2: reduce 512 partial rows, emit per-channel scale/shift ----
template<int CH>
__global__ __launch_bounds__(256) void stats_fin(const float* __restrict__ partials,
                                                 const float* __restrict__ g,
                                                 const float* __restrict__ bet,
                                                 float* __restrict__ sab){
  const int t = threadIdx.x;
  __shared__ float red[2 * CH];
  if (t < 2 * CH){
    float a = 0.f;
#pragma unroll 8
    for (int r = 0; r < 512; r++) a += partials[(size_t)r * (2 * CH) + t];
    red[t] = a;
  }
  __syncthreads();
  if (t < CH){
    constexpr float inv = 1.f / (float)((size_t)B_ * S_ * K_);
    float mean = red[t] * inv;
    float var  = red[CH + t] * inv - mean * mean;
    float r    = 1.f / sqrtf(var + BN_EPS_);
    float a    = r * g[t];
    sab[t] = a;
    sab[CH + t] = bet[t] - mean * a;
  }
}

// ---- final: bn3(+relu) on bf16 pre-BN max/min (monotone-affine dispatch) ----
__global__ __launch_bounds__(256) void final_kernel(const unsigned short* __restrict__ m3max,
                                                    const unsigned short* __restrict__ m3min,
                                                    const float* __restrict__ sab3,
                                                    float* __restrict__ outNF){
  const int q = blockIdx.x * 256 + threadIdx.x;   // quad index over B*128*1024/4
  const int e = q * 4;
  const int o = (e >> 10) & 127;
  const float a = sab3[o], c = sab3[128 + o];
  const ushort4 mx = ((const ushort4*)m3max)[q];
  const ushort4 mn = ((const ushort4*)m3min)[q];
  float4 r;
  r.x = fmaxf(fmaf(bfu(a >= 0.f ? mx.x : mn.x), a, c), 0.f);
  r.y = fmaxf(fmaf(bfu(a >= 0.f ? mx.y : mn.y), a, c), 0.f);
  r.z = fmaxf(fmaf(bfu(a >= 0.f ? mx.z : mn.z), a, c), 0.f);
  r.w = fmaxf(fmaf(bfu(a >= 0.f ? mx.w : mn.w), a, c), 0.f);
  ((float4*)outNF)[q] = r;
}

extern "C" void kernel_launch(void* const* d_in, const int* in_sizes, int n_in,
                              void* d_out, int out_size, void* d_ws, size_t ws_size,
                              hipStream_t stream){
  (void)in_sizes; (void)n_in; (void)out_size;
  const float* xyz = (const float*)d_in[0];
  const float* feat = (const float*)d_in[1];
  const float* W1 = (const float*)d_in[2];
  const float* g1 = (const float*)d_in[3];
  const float* b1 = (const float*)d_in[4];
  const float* W2 = (const float*)d_in[5];
  const float* g2 = (const float*)d_in[6];
  const float* b2 = (const float*)d_in[7];
  const float* W3 = (const float*)d_in[8];
  const float* g3 = (const float*)d_in[9];
  const float* b3 = (const float*)d_in[10];

  float* newxyz = (float*)d_out;                       // (B,S,3)
  float* outNF  = newxyz + (size_t)B_ * S_ * 3;        // (B,128,S)
  char* ws = (char*)d_ws;

  size_t off = 0;
  auto alloc = [&](size_t bytes){ size_t o = off; off += (bytes + 255) & ~(size_t)255; return o; };
  size_t o_idx  = alloc((size_t)B_ * S_ * K_ * 4);           // 2 MB
  size_t o_part = alloc((size_t)512 * 256 * 4);              // 512 KB
  size_t o_sab1 = alloc(1024);
  size_t o_sab2 = alloc(1024);
  size_t o_sab3 = alloc(1024);
  size_t o_m3mx = alloc((size_t)B_ * S_ * 128 * 2);          // 4 MB (bf16)
  size_t o_m3mn = alloc((size_t)B_ * S_ * 128 * 2);          // 4 MB (bf16)
  size_t o_featT = alloc((size_t)B_ * N_ * C_ * 2);          // 8 MB (bf16)
  const bool ft = ws_size >= off;                            // 19.4 MB total

  int*   idxp  = (int*)(ws + o_idx);
  float* part  = (float*)(ws + o_part);
  float* sab1  = (float*)(ws + o_sab1);
  float* sab2  = (float*)(ws + o_sab2);
  float* sab3  = (float*)(ws + o_sab3);
  unsigned short* m3mx  = (unsigned short*)(ws + o_m3mx);
  unsigned short* m3mn  = (unsigned short*)(ws + o_m3mn);
  unsigned short* featT = (unsigned short*)(ws + o_featT);

  if (ft) transpose_kernel<<<dim3(N_ / 32, B_), dim3(32, 8), 0, stream>>>(feat, featT);
  fps_kernel<<<B_, 256, 0, stream>>>(xyz, newxyz);
  ballq_kernel<<<B_ * S_ / 4, 256, 0, stream>>>(xyz, newxyz, idxp);

  if (ft){
    pass_kernel<1, true><<<512, 512, 0, stream>>>(xyz, feat, featT, newxyz, idxp,
        W1, W2, W3, sab1, sab2, part, m3mx, m3mn);
    stats_fin<64><<<1, 256, 0, stream>>>(part, g1, b1, sab1);
    pass_kernel<2, true><<<512, 512, 0, stream>>>(xyz, feat, featT, newxyz, idxp,
        W1, W2, W3, sab1, sab2, part, m3mx, m3mn);
    stats_fin<64><<<1, 256, 0, stream>>>(part, g2, b2, sab2);
    pass_kernel<3, true><<<512, 512, 0, stream>>>(xyz, feat, featT, newxyz, idxp,
        W1, W2, W3, sab1, sab2, part, m3mx, m3mn);
    stats_fin<128><<<1, 256, 0, stream>>>(part, g3, b3, sab3);
  } else {
    pass_kernel<1, false><<<512, 512, 0, stream>>>(xyz, feat, featT, newxyz, idxp,
        W1, W2, W3, sab1, sab2, part, m3mx, m3mn);
    stats_fin<64><<<1, 256, 0, stream>>>(part, g1, b1, sab1);
    pass_kernel<2, false><<<512, 512, 0, stream>>>(xyz, feat, featT, newxyz, idxp,
        W1, W2, W3, sab1, sab2, part, m3mx, m3mn);
    stats_fin<64><<<1, 256, 0, stream>>>(part, g2, b2, sab2);
    pass_kernel<3, false><<<512, 512, 0, stream>>>(xyz, feat, featT, newxyz, idxp,
        W1, W2, W3, sab1, sab2, part, m3mx, m3mn);
    stats_fin<128><<<1, 256, 0, stream>>>(part, g3, b3, sab3);
  }
  final_kernel<<<(B_ * 128 * S_) / 1024, 256, 0, stream>>>(m3mx, m3mn, sab3, outNF);
}

// Round 16
// 1501.391 us; speedup vs baseline: 1.2519x; 1.1072x over previous
//
#include <hip/hip_runtime.h>
#include <hip/hip_bf16.h>

// ---- problem constants ----
static constexpr int B_ = 16;
static constexpr int N_ = 8192;
static constexpr int C_ = 32;     // input feature channels
static constexpr int S_ = 1024;   // NPOINT
static constexpr int K_ = 32;     // NSAMPLE
static constexpr float BN_EPS_ = 1e-5f;

typedef float f32x2 __attribute__((ext_vector_type(2)));

__device__ __forceinline__ unsigned short f2bf(float f){
  unsigned u = __float_as_uint(f);
  unsigned r = (u + 0x7fffu + ((u >> 16) & 1u)) >> 16;
  return (unsigned short)r;
}
__device__ __forceinline__ float bflo(unsigned u){ return __int_as_float(u << 16); }
__device__ __forceinline__ float bfhi(unsigned u){ return __int_as_float(u & 0xffff0000u); }
__device__ __forceinline__ float bfu(unsigned short u){ return __int_as_float(((unsigned)u) << 16); }

// rocPRIM-standard wave64 DPP reduce step on a u64 key (HW-proven R9-R15).
template<int CTRL>
__device__ __forceinline__ unsigned long long dpp64(unsigned long long v){
  int lo = (int)(unsigned)(v & 0xffffffffull);
  int hi = (int)(unsigned)(v >> 32);
  int lo2 = __builtin_amdgcn_update_dpp(lo, lo, CTRL, 0xf, 0xf, false);
  int hi2 = __builtin_amdgcn_update_dpp(hi, hi, CTRL, 0xf, 0xf, false);
  return (((unsigned long long)(unsigned)hi2) << 32) | (unsigned)lo2;
}
__device__ __forceinline__ unsigned long long u64max(unsigned long long a,
                                                     unsigned long long b){
  return a > b ? a : b;
}

// ---- features (B,C,N) f32 -> featT (B,N,C) bf16 ----
__global__ __launch_bounds__(256) void transpose_kernel(const float* __restrict__ feat,
                                                        unsigned short* __restrict__ featT){
  __shared__ float tile[32][33];
  const int b = blockIdx.y;
  const int n0 = blockIdx.x * 32;
  const int tx = threadIdx.x, ty = threadIdx.y;
#pragma unroll
  for (int i = 0; i < 4; i++){
    int c = ty + i * 8;
    tile[c][tx] = feat[((size_t)b * C_ + c) * N_ + n0 + tx];
  }
  __syncthreads();
#pragma unroll
  for (int i = 0; i < 4; i++){
    int r = ty + i * 8;
    featT[((size_t)b * N_ + n0 + r) * C_ + tx] = f2bf(tile[tx][r]);
  }
}

// ---- furthest point sampling: 1 block/batch, 256 threads, 1 barrier/iter ----
// R14/R15 HW-proven version, byte-identical (881 us, plateaued).
__global__ __launch_bounds__(256) void fps_kernel(const float* __restrict__ xyz,
                                                  float* __restrict__ newxyz){
  const int b = blockIdx.x, t = threadIdx.x;      // t in [0,256)
  const float* px = xyz + (size_t)b * N_ * 3;
  __shared__ float pl[N_ * 3];                    // 96 KB copy of the batch
  __shared__ unsigned long long slots[2][4];      // [parity][wave]

  for (int i = t; i < N_ * 3 / 4; i += 256)
    ((float4*)pl)[i] = ((const float4*)px)[i];

  f32x2 X2[16], Y2[16], Z2[16], MD2[16];
#pragma unroll
  for (int q = 0; q < 16; q++){
    const int p0 = 512 * q + t, p1 = 512 * q + 256 + t;
    float x0 = px[3 * p0 + 0], y0 = px[3 * p0 + 1], z0 = px[3 * p0 + 2];
    float x1 = px[3 * p1 + 0], y1 = px[3 * p1 + 1], z1 = px[3 * p1 + 2];
    asm volatile("" : "+v"(x0), "+v"(y0), "+v"(z0),
                      "+v"(x1), "+v"(y1), "+v"(z1));   // pin SCALARS in VGPRs
    X2[q] = f32x2{x0, x1};
    Y2[q] = f32x2{y0, y1};
    Z2[q] = f32x2{z0, z1};
    MD2[q] = f32x2{1e10f, 1e10f};
  }
  if (t == 0){
    size_t o = (size_t)b * S_ * 3;
    newxyz[o] = px[0]; newxyz[o + 1] = px[1]; newxyz[o + 2] = px[2];
  }
  float cx = px[0], cy = px[1], cz = px[2];
  __syncthreads();                                // covers pl copy

  for (int i = 1; i < S_; i++){
    const int p = i & 1;
    const f32x2 cx2 = {cx, cx}, cy2 = {cy, cy}, cz2 = {cz, cz};
    float tmax = -1.f;
#pragma unroll
    for (int q = 0; q < 16; q++){
      f32x2 dx = X2[q] - cx2;                     // per-half rn sub
      f32x2 dy = Y2[q] - cy2;
      f32x2 dz = Z2[q] - cz2;
      f32x2 dd = (dx * dx + dy * dy) + dz * dz;   // exact reference op order
      f32x2 m;
      m[0] = fminf(MD2[q][0], dd[0]);
      m[1] = fminf(MD2[q][1], dd[1]);
      MD2[q] = m;
      tmax = fmaxf(tmax, fmaxf(m[0], m[1]));      // v_max3-fusable
    }
    unsigned cand = 0;
#pragma unroll
    for (int q = 15; q >= 0; q--){
      if (MD2[q][1] == tmax) cand = (unsigned)(512 * q + 256 + t);
      if (MD2[q][0] == tmax) cand = (unsigned)(512 * q + t);
    }
    unsigned long long key = ((unsigned long long)__float_as_uint(tmax) << 32)
                           | (unsigned long long)(8191u - cand);
    key = u64max(key, dpp64<0xb1>(key));          // quad_perm [1,0,3,2]
    key = u64max(key, dpp64<0x4e>(key));          // quad_perm [2,3,0,1]
    key = u64max(key, dpp64<0x114>(key));         // row_shr:4
    key = u64max(key, dpp64<0x118>(key));         // row_shr:8
    key = u64max(key, dpp64<0x142>(key));         // row_bcast:15
    key = u64max(key, dpp64<0x143>(key));         // row_bcast:31
    if ((t & 63) == 63) slots[p][t >> 6] = key;   // plain write, 1 per wave
    __syncthreads();
    unsigned long long best = u64max(u64max(slots[p][0], slots[p][1]),
                                     u64max(slots[p][2], slots[p][3]));
    const int fi = 8191 - (int)(best & 0xffffu);
    cx = pl[3 * fi]; cy = pl[3 * fi + 1]; cz = pl[3 * fi + 2];  // LDS broadcast
    if (t == 0){
      size_t o = ((size_t)b * S_ + i) * 3;
      newxyz[o] = cx; newxyz[o + 1] = cy; newxyz[o + 2] = cz;
    }
  }
}

// ---- ball query: 1 wave per centroid ----
__global__ __launch_bounds__(256) void ballq_kernel(const float* __restrict__ xyz,
                                                    const float* __restrict__ newxyz,
                                                    int* __restrict__ idxout){
  const int wave = threadIdx.x >> 6, lane = threadIdx.x & 63;
  const int cid = blockIdx.x * 4 + wave;
  const int b = cid >> 10;
  const float cx = newxyz[(size_t)cid * 3];
  const float cy = newxyz[(size_t)cid * 3 + 1];
  const float cz = newxyz[(size_t)cid * 3 + 2];
  const float* px = xyz + (size_t)b * N_ * 3;
  __shared__ int buf[4][32];
  const float r2 = 0.04f;   // fp32(double(0.2*0.2)) == 0x3D23D70A
  int have = 0;
  for (int base = 0; base < N_ && have < 32; base += 64){
    int p = base + lane;
    float dx = __fsub_rn(cx, px[3 * p]);
    float dy = __fsub_rn(cy, px[3 * p + 1]);
    float dz = __fsub_rn(cz, px[3 * p + 2]);
    float sq = __fadd_rn(__fadd_rn(__fmul_rn(dx, dx), __fmul_rn(dy, dy)), __fmul_rn(dz, dz));
    bool pred = sq < r2;
    unsigned long long m = __ballot(pred);
    if (pred){
      int pos = have + __popcll(m & ((1ull << lane) - 1ull));
      if (pos < 32) buf[wave][pos] = p;
    }
    have += (int)__popcll(m);
  }
  __syncthreads();
  if (lane < 32){
    int first = buf[wave][0];
    int v = (lane < have) ? buf[wave][lane] : first;
    idxout[(size_t)cid * 32 + lane] = v;
  }
}

// ---- LDS arena layout for the recompute pass kernels (all f32) ----
template<int DEPTH>
struct PassLds {
  static constexpr int XS  = 0;                 // [32][36] f32 (x tile, col35 zeroed)
  static constexpr int W1O = XS + 32 * 36;      // [64][36] f32 (col35 zeroed)
  static constexpr int HA  = W1O + 64 * 36;     // [32][68] f32 (DEPTH>=2)
  static constexpr int W2O = HA + 32 * 68;      // [64][64] f32, chunk-XOR swizzled
  static constexpr int HB  = W2O + 64 * 64;     // [32][68] f32 (DEPTH==3)
  static constexpr int W3O = HB + 32 * 68;      // [128][64] f32, chunk-XOR swizzled
  static constexpr int FLOATS = (DEPTH == 1) ? (W1O + 64 * 36)
                             : (DEPTH == 2) ? (W2O + 64 * 64)
                             : (W3O + 128 * 64);   // D3: 20096 floats = 80384 B
};

// ---- fused recompute pass (512 threads) ----
// Gather mapping: grow = t&31 (sample row), ggrp = t>>5 (16 groups).
// Compute mapping (NEW, register-blocked): rb = t&15, og = t>>4 (32 groups).
// Each thread computes rows {rb, rb+16} x {2 (mm1/mm2) or 4 (mm3)} channels:
// weight reads amortize over 2 rows -> LDS wave-insts -27%. W2/W3 stored with
// 16B-chunk XOR swizzle ((c>>2)^((r>>1 or >>2)&3)) so the 4 distinct weight
// rows a wave reads simultaneously hit disjoint banks (was 4-way conflict).
// Stats / min-max reduce over the 16 rb lanes (shfl_xor 1..8), rb==0 writes.
template<int DEPTH, bool FT>
__global__ __launch_bounds__(512, 4) void pass_kernel(
    const float* __restrict__ xyz, const float* __restrict__ feat,
    const unsigned short* __restrict__ featT, const float* __restrict__ newxyz,
    const int* __restrict__ idx,
    const float* __restrict__ W1, const float* __restrict__ W2,
    const float* __restrict__ W3,
    const float* __restrict__ sab1, const float* __restrict__ sab2,
    float* __restrict__ partials,
    unsigned short* __restrict__ m3max, unsigned short* __restrict__ m3min){
  using L = PassLds<DEPTH>;
  __shared__ float sm[L::FLOATS];
  const int t = threadIdx.x;
  const int grow = t & 31, ggrp = t >> 5;   // gather mapping
  const int rb = t & 15, og = t >> 4;       // compute mapping (og in [0,32))

  // ---- stage weights once per block ----
  for (int i = t; i < 64 * 36; i += 512){
    int o = i / 36, c = i - o * 36;
    sm[L::W1O + i] = (c < 35) ? W1[o * 35 + c] : 0.f;
  }
  if constexpr (DEPTH >= 2){
    for (int i = t; i < 64 * 64; i += 512){
      int r = i >> 6, c = i & 63;
      sm[L::W2O + (r << 6) + ((((c >> 2) ^ ((r >> 1) & 3)) << 2) | (c & 3))] = W2[i];
    }
  }
  if constexpr (DEPTH == 3){
    for (int i = t; i < 128 * 64; i += 512){
      int r = i >> 6, c = i & 63;
      sm[L::W3O + (r << 6) + ((((c >> 2) ^ ((r >> 2) & 3)) << 2) | (c & 3))] = W3[i];
    }
  }

  // ---- per-thread BN params ----
  float sa1[2], sb1[2], sa2[2], sb2[2];
  if constexpr (DEPTH >= 2){
#pragma unroll
    for (int u = 0; u < 2; u++){ sa1[u] = sab1[og * 2 + u]; sb1[u] = sab1[64 + og * 2 + u]; }
  }
  if constexpr (DEPTH == 3){
#pragma unroll
    for (int u = 0; u < 2; u++){ sa2[u] = sab2[og * 2 + u]; sb2[u] = sab2[64 + og * 2 + u]; }
  }

  constexpr int US = (DEPTH == 3) ? 4 : 2;     // stats channels per thread
  float stS[US], stQ[US];
#pragma unroll
  for (int u = 0; u < US; u++){ stS[u] = 0.f; stQ[u] = 0.f; }

  // ---- prefetch state (registers) ----
  uint4 pfeat = {0, 0, 0, 0};
  float pf0 = 0.f, pf1 = 0.f, pf2 = 0.f, pf3 = 0.f;
  float prx = 0.f, pry = 0.f, prz = 0.f;

  auto prefetch = [&](int it2){
    const int g2 = blockIdx.x * 32 + it2;
    const int b2 = g2 >> 10;
    if constexpr (FT){
      if (ggrp < 4){
        const int id = idx[(size_t)g2 * 32 + grow];
        pfeat = *(const uint4*)(featT + ((size_t)b2 * N_ + id) * C_ + ggrp * 8);
      } else if (ggrp == 4){
        const int id = idx[(size_t)g2 * 32 + grow];
        size_t pb = ((size_t)b2 * N_ + id) * 3;
        prx = __fsub_rn(xyz[pb + 0], newxyz[(size_t)g2 * 3 + 0]);
        pry = __fsub_rn(xyz[pb + 1], newxyz[(size_t)g2 * 3 + 1]);
        prz = __fsub_rn(xyz[pb + 2], newxyz[(size_t)g2 * 3 + 2]);
      }
    } else {
      if (ggrp < 8){
        const int id = idx[(size_t)g2 * 32 + grow];
        pf0 = feat[((size_t)b2 * C_ + ggrp * 4 + 0) * N_ + id];
        pf1 = feat[((size_t)b2 * C_ + ggrp * 4 + 1) * N_ + id];
        pf2 = feat[((size_t)b2 * C_ + ggrp * 4 + 2) * N_ + id];
        pf3 = feat[((size_t)b2 * C_ + ggrp * 4 + 3) * N_ + id];
      } else if (ggrp == 8){
        const int id = idx[(size_t)g2 * 32 + grow];
        size_t pb = ((size_t)b2 * N_ + id) * 3;
        prx = __fsub_rn(xyz[pb + 0], newxyz[(size_t)g2 * 3 + 0]);
        pry = __fsub_rn(xyz[pb + 1], newxyz[(size_t)g2 * 3 + 1]);
        prz = __fsub_rn(xyz[pb + 2], newxyz[(size_t)g2 * 3 + 2]);
      }
    }
  };
  auto commit_xs = [&](){
    float* xr = &sm[L::XS + grow * 36];
    if constexpr (FT){
      if (ggrp < 4){
        xr[3 + ggrp * 8 + 0] = bflo(pfeat.x); xr[3 + ggrp * 8 + 1] = bfhi(pfeat.x);
        xr[3 + ggrp * 8 + 2] = bflo(pfeat.y); xr[3 + ggrp * 8 + 3] = bfhi(pfeat.y);
        xr[3 + ggrp * 8 + 4] = bflo(pfeat.z); xr[3 + ggrp * 8 + 5] = bfhi(pfeat.z);
        xr[3 + ggrp * 8 + 6] = bflo(pfeat.w); xr[3 + ggrp * 8 + 7] = bfhi(pfeat.w);
      } else if (ggrp == 4){
        xr[0] = prx; xr[1] = pry; xr[2] = prz; xr[35] = 0.f;
      }
    } else {
      if (ggrp < 8){
        xr[3 + ggrp * 4 + 0] = pf0; xr[3 + ggrp * 4 + 1] = pf1;
        xr[3 + ggrp * 4 + 2] = pf2; xr[3 + ggrp * 4 + 3] = pf3;
      } else if (ggrp == 8){
        xr[0] = prx; xr[1] = pry; xr[2] = prz; xr[35] = 0.f;
      }
    }
  };

  prefetch(0);
  commit_xs();
  __syncthreads();    // covers weights + xs(0)

  for (int it = 0; it < 32; ++it){
    const int g = blockIdx.x * 32 + it;
    const int b = g >> 10;
    if (it < 31) prefetch(it + 1);              // issue next group's loads

    // ---- mm1: rows {rb, rb+16} x outs {og*2, og*2+1} ----
    float a00 = 0.f, a01 = 0.f, a10 = 0.f, a11 = 0.f;
#pragma unroll 3
    for (int cb = 0; cb < 36; cb += 4){
      const float4 x0 = *(const float4*)&sm[L::XS + rb * 36 + cb];
      const float4 x1 = *(const float4*)&sm[L::XS + (rb + 16) * 36 + cb];
      const float4 w0 = *(const float4*)&sm[L::W1O + (og * 2 + 0) * 36 + cb];
      const float4 w1 = *(const float4*)&sm[L::W1O + (og * 2 + 1) * 36 + cb];
      a00 = fmaf(x0.x, w0.x, a00); a00 = fmaf(x0.y, w0.y, a00);
      a00 = fmaf(x0.z, w0.z, a00); a00 = fmaf(x0.w, w0.w, a00);
      a01 = fmaf(x0.x, w1.x, a01); a01 = fmaf(x0.y, w1.y, a01);
      a01 = fmaf(x0.z, w1.z, a01); a01 = fmaf(x0.w, w1.w, a01);
      a10 = fmaf(x1.x, w0.x, a10); a10 = fmaf(x1.y, w0.y, a10);
      a10 = fmaf(x1.z, w0.z, a10); a10 = fmaf(x1.w, w0.w, a10);
      a11 = fmaf(x1.x, w1.x, a11); a11 = fmaf(x1.y, w1.y, a11);
      a11 = fmaf(x1.z, w1.z, a11); a11 = fmaf(x1.w, w1.w, a11);
    }
    if constexpr (DEPTH == 1){
      stS[0] += a00 + a10; stQ[0] = fmaf(a00, a00, stQ[0]); stQ[0] = fmaf(a10, a10, stQ[0]);
      stS[1] += a01 + a11; stQ[1] = fmaf(a01, a01, stQ[1]); stQ[1] = fmaf(a11, a11, stQ[1]);
      __syncthreads();                          // all mm1 reads of xs done
      if (it < 31) commit_xs();
      __syncthreads();                          // xs(it+1) visible
      continue;
    }

    // ---- bn1 + relu -> hA ----
    sm[L::HA + rb * 68 + og * 2 + 0]        = fmaxf(fmaf(a00, sa1[0], sb1[0]), 0.f);
    sm[L::HA + rb * 68 + og * 2 + 1]        = fmaxf(fmaf(a01, sa1[1], sb1[1]), 0.f);
    sm[L::HA + (rb + 16) * 68 + og * 2 + 0] = fmaxf(fmaf(a10, sa1[0], sb1[0]), 0.f);
    sm[L::HA + (rb + 16) * 68 + og * 2 + 1] = fmaxf(fmaf(a11, sa1[1], sb1[1]), 0.f);
    __syncthreads();                            // HA ready; xs dead
    if (it < 31) commit_xs();                   // overlap with mm2/mm3

    // ---- mm2: rows {rb, rb+16} x outs {og*2, og*2+1}, W2 swizzled ----
    float c00 = 0.f, c01 = 0.f, c10 = 0.f, c11 = 0.f;
#pragma unroll 4
    for (int cb = 0; cb < 64; cb += 4){
      const float4 x0 = *(const float4*)&sm[L::HA + rb * 68 + cb];
      const float4 x1 = *(const float4*)&sm[L::HA + (rb + 16) * 68 + cb];
      const int r0 = og * 2 + 0, r1 = og * 2 + 1;
      const float4 w0 = *(const float4*)&sm[L::W2O + (r0 << 6) + (((cb >> 2) ^ ((r0 >> 1) & 3)) << 2)];
      const float4 w1 = *(const float4*)&sm[L::W2O + (r1 << 6) + (((cb >> 2) ^ ((r1 >> 1) & 3)) << 2)];
      c00 = fmaf(x0.x, w0.x, c00); c00 = fmaf(x0.y, w0.y, c00);
      c00 = fmaf(x0.z, w0.z, c00); c00 = fmaf(x0.w, w0.w, c00);
      c01 = fmaf(x0.x, w1.x, c01); c01 = fmaf(x0.y, w1.y, c01);
      c01 = fmaf(x0.z, w1.z, c01); c01 = fmaf(x0.w, w1.w, c01);
      c10 = fmaf(x1.x, w0.x, c10); c10 = fmaf(x1.y, w0.y, c10);
      c10 = fmaf(x1.z, w0.z, c10); c10 = fmaf(x1.w, w0.w, c10);
      c11 = fmaf(x1.x, w1.x, c11); c11 = fmaf(x1.y, w1.y, c11);
      c11 = fmaf(x1.z, w1.z, c11); c11 = fmaf(x1.w, w1.w, c11);
    }
    if constexpr (DEPTH == 2){
      stS[0] += c00 + c10; stQ[0] = fmaf(c00, c00, stQ[0]); stQ[0] = fmaf(c10, c10, stQ[0]);
      stS[1] += c01 + c11; stQ[1] = fmaf(c01, c01, stQ[1]); stQ[1] = fmaf(c11, c11, stQ[1]);
      __syncthreads();                          // orders xs commit + HA reuse
      continue;
    }

    if constexpr (DEPTH == 3){
      // ---- bn2 + relu -> hB ----
      sm[L::HB + rb * 68 + og * 2 + 0]        = fmaxf(fmaf(c00, sa2[0], sb2[0]), 0.f);
      sm[L::HB + rb * 68 + og * 2 + 1]        = fmaxf(fmaf(c01, sa2[1], sb2[1]), 0.f);
      sm[L::HB + (rb + 16) * 68 + og * 2 + 0] = fmaxf(fmaf(c10, sa2[0], sb2[0]), 0.f);
      sm[L::HB + (rb + 16) * 68 + og * 2 + 1] = fmaxf(fmaf(c11, sa2[1], sb2[1]), 0.f);
      __syncthreads();                          // HB ready; xs commit visible

      // ---- mm3: rows {rb, rb+16} x outs {og*4..og*4+3}, W3 swizzled ----
      float d0[4] = {0.f, 0.f, 0.f, 0.f};
      float d1[4] = {0.f, 0.f, 0.f, 0.f};
#pragma unroll 2
      for (int cb = 0; cb < 64; cb += 4){
        const float4 x0 = *(const float4*)&sm[L::HB + rb * 68 + cb];
        const float4 x1 = *(const float4*)&sm[L::HB + (rb + 16) * 68 + cb];
#pragma unroll
        for (int u = 0; u < 4; u++){
          const int r = og * 4 + u;
          const float4 wv = *(const float4*)&sm[L::W3O + (r << 6) + (((cb >> 2) ^ ((r >> 2) & 3)) << 2)];
          d0[u] = fmaf(x0.x, wv.x, d0[u]); d0[u] = fmaf(x0.y, wv.y, d0[u]);
          d0[u] = fmaf(x0.z, wv.z, d0[u]); d0[u] = fmaf(x0.w, wv.w, d0[u]);
          d1[u] = fmaf(x1.x, wv.x, d1[u]); d1[u] = fmaf(x1.y, wv.y, d1[u]);
          d1[u] = fmaf(x1.z, wv.z, d1[u]); d1[u] = fmaf(x1.w, wv.w, d1[u]);
        }
      }
#pragma unroll
      for (int u = 0; u < 4; u++){
        stS[u] += d0[u] + d1[u];
        stQ[u] = fmaf(d0[u], d0[u], stQ[u]);
        stQ[u] = fmaf(d1[u], d1[u], stQ[u]);
      }

      // ---- pre-BN max/min over the 32 rows (16 rb lanes x 2 rows) ----
      const int s = g & 1023;
#pragma unroll
      for (int u = 0; u < 4; u++){
        float mx = fmaxf(d0[u], d1[u]);
        float mn = fminf(d0[u], d1[u]);
#pragma unroll
        for (int m = 1; m < 16; m <<= 1){
          mx = fmaxf(mx, __shfl_xor(mx, m));
          mn = fminf(mn, __shfl_xor(mn, m));
        }
        if (rb == 0){
          size_t o = ((size_t)b * 128 + og * 4 + u) * 1024 + s;
          m3max[o] = f2bf(mx); m3min[o] = f2bf(mn);
        }
      }
    }
  }

  // ---- block stats partials: reduce over the 16 rb lanes ----
#pragma unroll
  for (int m = 1; m < 16; m <<= 1){
#pragma unroll
    for (int u = 0; u < US; u++){
      stS[u] += __shfl_xor(stS[u], m);
      stQ[u] += __shfl_xor(stQ[u], m);
    }
  }
  if (rb == 0){
    constexpr int CH = (DEPTH == 3) ? 128 : 64;
    float* p = partials + (size_t)blockIdx.x * (2 * CH);
    const int o0 = og * US;
#pragma unroll
    for (int u = 0; u < US; u++){ p[o0 + u] = stS[u]; p[CH + o0 + u] = stQ[u]; }
  }
}

// ---- stats stage 2: reduce 512 partial rows, emit per-channel scale/shift ----
template<int CH>
__global__ __launch_bounds__(256) void stats_fin(const float* __restrict__ partials,
                                                 const float* __restrict__ g,
                                                 const float* __restrict__ bet,
                                                 float* __restrict__ sab){
  const int t = threadIdx.x;
  __shared__ float red[2 * CH];
  if (t < 2 * CH){
    float a = 0.f;
#pragma unroll 8
    for (int r = 0; r < 512; r++) a += partials[(size_t)r * (2 * CH) + t];
    red[t] = a;
  }
  __syncthreads();
  if (t < CH){
    constexpr float inv = 1.f / (float)((size_t)B_ * S_ * K_);
    float mean = red[t] * inv;
    float var  = red[CH + t] * inv - mean * mean;
    float r    = 1.f / sqrtf(var + BN_EPS_);
    float a    = r * g[t];
    sab[t] = a;
    sab[CH + t] = bet[t] - mean * a;
  }
}

// ---- final: bn3(+relu) on bf16 pre-BN max/min (monotone-affine dispatch) ----
__global__ __launch_bounds__(256) void final_kernel(const unsigned short* __restrict__ m3max,
                                                    const unsigned short* __restrict__ m3min,
                                                    const float* __restrict__ sab3,
                                                    float* __restrict__ outNF){
  const int q = blockIdx.x * 256 + threadIdx.x;   // quad index over B*128*1024/4
  const int e = q * 4;
  const int o = (e >> 10) & 127;
  const float a = sab3[o], c = sab3[128 + o];
  const ushort4 mx = ((const ushort4*)m3max)[q];
  const ushort4 mn = ((const ushort4*)m3min)[q];
  float4 r;
  r.x = fmaxf(fmaf(bfu(a >= 0.f ? mx.x : mn.x), a, c), 0.f);
  r.y = fmaxf(fmaf(bfu(a >= 0.f ? mx.y : mn.y), a, c), 0.f);
  r.z = fmaxf(fmaf(bfu(a >= 0.f ? mx.z : mn.z), a, c), 0.f);
  r.w = fmaxf(fmaf(bfu(a >= 0.f ? mx.w : mn.w), a, c), 0.f);
  ((float4*)outNF)[q] = r;
}

extern "C" void kernel_launch(void* const* d_in, const int* in_sizes, int n_in,
                              void* d_out, int out_size, void* d_ws, size_t ws_size,
                              hipStream_t stream){
  (void)in_sizes; (void)n_in; (void)out_size;
  const float* xyz = (const float*)d_in[0];
  const float* feat = (const float*)d_in[1];
  const float* W1 = (const float*)d_in[2];
  const float* g1 = (const float*)d_in[3];
  const float* b1 = (const float*)d_in[4];
  const float* W2 = (const float*)d_in[5];
  const float* g2 = (const float*)d_in[6];
  const float* b2 = (const float*)d_in[7];
  const float* W3 = (const float*)d_in[8];
  const float* g3 = (const float*)d_in[9];
  const float* b3 = (const float*)d_in[10];

  float* newxyz = (float*)d_out;                       // (B,S,3)
  float* outNF  = newxyz + (size_t)B_ * S_ * 3;        // (B,128,S)
  char* ws = (char*)d_ws;

  size_t off = 0;
  auto alloc = [&](size_t bytes){ size_t o = off; off += (bytes + 255) & ~(size_t)255; return o; };
  size_t o_idx  = alloc((size_t)B_ * S_ * K_ * 4);           // 2 MB
  size_t o_part = alloc((size_t)512 * 256 * 4);              // 512 KB
  size_t o_sab1 = alloc(1024);
  size_t o_sab2 = alloc(1024);
  size_t o_sab3 = alloc(1024);
  size_t o_m3mx = alloc((size_t)B_ * S_ * 128 * 2);          // 4 MB (bf16)
  size_t o_m3mn = alloc((size_t)B_ * S_ * 128 * 2);          // 4 MB (bf16)
  size_t o_featT = alloc((size_t)B_ * N_ * C_ * 2);          // 8 MB (bf16)
  const bool ft = ws_size >= off;                            // 19.4 MB total

  int*   idxp  = (int*)(ws + o_idx);
  float* part  = (float*)(ws + o_part);
  float* sab1  = (float*)(ws + o_sab1);
  float* sab2  = (float*)(ws + o_sab2);
  float* sab3  = (float*)(ws + o_sab3);
  unsigned short* m3mx  = (unsigned short*)(ws + o_m3mx);
  unsigned short* m3mn  = (unsigned short*)(ws + o_m3mn);
  unsigned short* featT = (unsigned short*)(ws + o_featT);

  if (ft) transpose_kernel<<<dim3(N_ / 32, B_), dim3(32, 8), 0, stream>>>(feat, featT);
  fps_kernel<<<B_, 256, 0, stream>>>(xyz, newxyz);
  ballq_kernel<<<B_ * S_ / 4, 256, 0, stream>>>(xyz, newxyz, idxp);

  if (ft){
    pass_kernel<1, true><<<512, 512, 0, stream>>>(xyz, feat, featT, newxyz, idxp,
        W1, W2, W3, sab1, sab2, part, m3mx, m3mn);
    stats_fin<64><<<1, 256, 0, stream>>>(part, g1, b1, sab1);
    pass_kernel<2, true><<<512, 512, 0, stream>>>(xyz, feat, featT, newxyz, idxp,
        W1, W2, W3, sab1, sab2, part, m3mx, m3mn);
    stats_fin<64><<<1, 256, 0, stream>>>(part, g2, b2, sab2);
    pass_kernel<3, true><<<512, 512, 0, stream>>>(xyz, feat, featT, newxyz, idxp,
        W1, W2, W3, sab1, sab2, part, m3mx, m3mn);
    stats_fin<128><<<1, 256, 0, stream>>>(part, g3, b3, sab3);
  } else {
    pass_kernel<1, false><<<512, 512, 0, stream>>>(xyz, feat, featT, newxyz, idxp,
        W1, W2, W3, sab1, sab2, part, m3mx, m3mn);
    stats_fin<64><<<1, 256, 0, stream>>>(part, g1, b1, sab1);
    pass_kernel<2, false><<<512, 512, 0, stream>>>(xyz, feat, featT, newxyz, idxp,
        W1, W2, W3, sab1, sab2, part, m3mx, m3mn);
    stats_fin<64><<<1, 256, 0, stream>>>(part, g2, b2, sab2);
    pass_kernel<3, false><<<512, 512, 0, stream>>>(xyz, feat, featT, newxyz, idxp,
        W1, W2, W3, sab1, sab2, part, m3mx, m3mn);
    stats_fin<128><<<1, 256, 0, stream>>>(part, g3, b3, sab3);
  }
  final_kernel<<<(B_ * 128 * S_) / 1024, 256, 0, stream>>>(m3mx, m3mn, sab3, outNF);
}